// Round 5
// baseline (3081.799 us; speedup 1.0000x reference)
//
#include <hip/hip_runtime.h>

// ---------------------------------------------------------------------------
// LRA_GNN: random-walk -> 8-head GAT -> 12-layer residual GCN -> FC.
// Round 5: GEMMs restructured for occupancy — wave w computes cols
// [16w,16w+16) of the block's 64 rows (acc[16]/lane, grid=N/64 -> ~24
// waves/CU vs 6). CSR counting-sort build + bf16 gather tables unchanged.
// ---------------------------------------------------------------------------

typedef unsigned int u32;

#define BSH 7              // bucket shift: 128 nodes per bucket
#define RNGB 128           // nodes per bucket
#define GEB 256            // edge-pass blocks

__device__ __forceinline__ float lrelu(float v) { return v > 0.f ? v : 0.2f * v; }
__device__ __forceinline__ float bf_lo(u32 w) { return __uint_as_float(w << 16); }
__device__ __forceinline__ float bf_hi(u32 w) { return __uint_as_float(w & 0xffff0000u); }
__device__ __forceinline__ u32 pack_bf16(float a, float b) {
  u32 ua = __float_as_uint(a); ua = ua + 0x7fffu + ((ua >> 16) & 1u);
  u32 ub = __float_as_uint(b); ub = ub + 0x7fffu + ((ub >> 16) & 1u);
  return (ua >> 16) | (ub & 0xffff0000u);
}

// --------------------- CSR build via bucketed counting sort ----------------

__global__ __launch_bounds__(256) void k_hist(
    const int* __restrict__ ei, int E, int NB, int chunk,
    int* __restrict__ gHistA, int* __restrict__ gHistB) {
  __shared__ int hA[1024], hB[1024];
  for (int i = threadIdx.x; i < NB; i += 256) { hA[i] = 0; hB[i] = 0; }
  __syncthreads();
  int e0 = blockIdx.x * chunk;
  int e1 = min(E, e0 + chunk);
  for (int e = e0 + threadIdx.x; e < e1; e += 256) {
    int s = ei[e], d = ei[E + e];
    atomicAdd(&hA[s >> BSH], 1);
    atomicAdd(&hB[d >> BSH], 1);
  }
  __syncthreads();
  for (int i = threadIdx.x; i < NB; i += 256) {
    gHistA[blockIdx.x * NB + i] = hA[i];
    gHistB[blockIdx.x * NB + i] = hB[i];
  }
}

__global__ __launch_bounds__(256) void k_colscan(
    int* __restrict__ gHist, int* __restrict__ tot, int NB) {
  __shared__ int s[GEB];
  int b = blockIdx.x;
  int t = threadIdx.x;
  int v = gHist[t * NB + b];
  s[t] = v;
  __syncthreads();
  for (int d = 1; d < GEB; d <<= 1) {
    int u = (t >= d) ? s[t - d] : 0;
    __syncthreads();
    s[t] += u;
    __syncthreads();
  }
  gHist[t * NB + b] = s[t] - v;
  if (t == GEB - 1) tot[b] = s[t];
}

__global__ __launch_bounds__(1024) void k_bscan(
    const int* __restrict__ totA, const int* __restrict__ totB,
    int* __restrict__ baseA, int* __restrict__ baseB,
    int* __restrict__ offA, int* __restrict__ offB, int NB, int N, int E) {
  __shared__ int sa[1024], sb[1024];
  int t = threadIdx.x;
  int va = (t < NB) ? totA[t] : 0;
  int vb = (t < NB) ? totB[t] : 0;
  sa[t] = va; sb[t] = vb;
  __syncthreads();
  for (int d = 1; d < 1024; d <<= 1) {
    int ua = (t >= d) ? sa[t - d] : 0;
    int ub = (t >= d) ? sb[t - d] : 0;
    __syncthreads();
    sa[t] += ua; sb[t] += ub;
    __syncthreads();
  }
  if (t < NB) { baseA[t] = sa[t] - va; baseB[t] = sb[t] - vb; }
  if (t == 0) { offA[N] = E; offB[N] = E; }
}

__global__ __launch_bounds__(256) void k_scatter(
    const int* __restrict__ ei, int E, int NB, int chunk,
    const int* __restrict__ gHistA, const int* __restrict__ gHistB,
    const int* __restrict__ baseA, const int* __restrict__ baseB,
    int2* __restrict__ pairsA, int2* __restrict__ pairsB) {
  __shared__ int cA[1024], cB[1024];
  int g = blockIdx.x;
  for (int i = threadIdx.x; i < NB; i += 256) {
    cA[i] = baseA[i] + gHistA[g * NB + i];
    cB[i] = baseB[i] + gHistB[g * NB + i];
  }
  __syncthreads();
  int e0 = g * chunk;
  int e1 = min(E, e0 + chunk);
  for (int e = e0 + threadIdx.x; e < e1; e += 256) {
    int s = ei[e], d = ei[E + e];
    int pa = atomicAdd(&cA[s >> BSH], 1);
    pairsA[pa] = {s, d};
    int pb = atomicAdd(&cB[d >> BSH], 1);
    pairsB[pb] = {s, d};
  }
}

template <int KEY>
__global__ __launch_bounds__(256) void k_bucket(
    const int2* __restrict__ pairs, const int* __restrict__ base,
    const int* __restrict__ tot, int* __restrict__ off,
    int* __restrict__ idx, float* __restrict__ dis, int N) {
  __shared__ int cnt[RNGB], pfx[RNGB];
  int b = blockIdx.x;
  int node0 = b << BSH;
  int rng = min(RNGB, N - node0);
  int bstart = base[b], bcount = tot[b];
  for (int i = threadIdx.x; i < rng; i += 256) cnt[i] = 0;
  __syncthreads();
  for (int i = threadIdx.x; i < bcount; i += 256) {
    int2 p = pairs[bstart + i];
    int loc = (KEY == 0 ? p.x : p.y) - node0;
    atomicAdd(&cnt[loc], 1);
  }
  __syncthreads();
  if (threadIdx.x == 0) {
    int run = 0;
    for (int i = 0; i < rng; ++i) { pfx[i] = run; run += cnt[i]; }
  }
  __syncthreads();
  for (int i = threadIdx.x; i < rng; i += 256) {
    off[node0 + i] = bstart + pfx[i];
    if (KEY == 1) dis[node0 + i] = rsqrtf((float)(cnt[i] + 1));
  }
  __syncthreads();
  for (int i = threadIdx.x; i < bcount; i += 256) {
    int2 p = pairs[bstart + i];
    int loc = (KEY == 0 ? p.x : p.y) - node0;
    int pos = bstart + atomicAdd(&pfx[loc], 1);
    idx[pos] = (KEY == 0 ? p.y : p.x);
  }
}

// --------------------------------- GEMMs -----------------------------------

// Block = 64 rows; wave w computes cols [16w,16w+16). lane = row.
__global__ __launch_bounds__(256) void k_gemm64(
    const float* __restrict__ X, const float* __restrict__ W,
    const float* __restrict__ dis, u32* __restrict__ Hb, int n) {
  int lane = threadIdx.x & 63;
  int w = threadIdx.x >> 6;
  int c0 = w * 16;
  int row = blockIdx.x * 64 + lane;
  bool valid = row < n;
  const float4* X4 = (const float4*)X;
  float acc[16];
#pragma unroll
  for (int c = 0; c < 16; ++c) acc[c] = 0.f;
  for (int k4 = 0; k4 < 16; ++k4) {
    float4 xv = valid ? X4[(size_t)row * 16 + k4] : float4{0.f, 0.f, 0.f, 0.f};
    float xs[4] = {xv.x, xv.y, xv.z, xv.w};
#pragma unroll
    for (int kk = 0; kk < 4; ++kk) {
      int k = k4 * 4 + kk;
      float xk = xs[kk];
#pragma unroll
      for (int c = 0; c < 16; ++c)
        acc[c] = fmaf(xk, W[k * 64 + c0 + c], acc[c]);
    }
  }
  if (!valid) return;
  float sc = dis[row];
  uint4* H4 = (uint4*)Hb;
  uint4 o0 = {pack_bf16(acc[0] * sc, acc[1] * sc), pack_bf16(acc[2] * sc, acc[3] * sc),
              pack_bf16(acc[4] * sc, acc[5] * sc), pack_bf16(acc[6] * sc, acc[7] * sc)};
  uint4 o1 = {pack_bf16(acc[8] * sc, acc[9] * sc), pack_bf16(acc[10] * sc, acc[11] * sc),
              pack_bf16(acc[12] * sc, acc[13] * sc), pack_bf16(acc[14] * sc, acc[15] * sc)};
  H4[(size_t)row * 8 + w * 2] = o0;
  H4[(size_t)row * 8 + w * 2 + 1] = o1;
}

// GAT projection from bf16 X. Wave w owns cols [16w,16w+16) = heads 2w,2w+1.
__global__ __launch_bounds__(256) void k_gat_gemm(
    const u32* __restrict__ Xb, const float* __restrict__ W,
    const float* __restrict__ asrc, const float* __restrict__ adst,
    u32* __restrict__ Hgb, float* __restrict__ al, int n) {
  int lane = threadIdx.x & 63;
  int w = threadIdx.x >> 6;
  int c0 = w * 16;
  int row = blockIdx.x * 64 + lane;
  bool valid = row < n;
  float acc[16];
#pragma unroll
  for (int c = 0; c < 16; ++c) acc[c] = 0.f;
  const uint4* X4 = (const uint4*)Xb;
  for (int k8 = 0; k8 < 8; ++k8) {
    uint4 xw = valid ? X4[(size_t)row * 8 + k8] : uint4{0u, 0u, 0u, 0u};
    float xs[8] = {bf_lo(xw.x), bf_hi(xw.x), bf_lo(xw.y), bf_hi(xw.y),
                   bf_lo(xw.z), bf_hi(xw.z), bf_lo(xw.w), bf_hi(xw.w)};
#pragma unroll
    for (int kk = 0; kk < 8; ++kk) {
      int k = k8 * 8 + kk;
      float xk = xs[kk];
#pragma unroll
      for (int c = 0; c < 16; ++c) {
        int gc = c0 + c;
        acc[c] = fmaf(xk, W[(gc >> 3) * 512 + k * 8 + (gc & 7)], acc[c]);
      }
    }
  }
  if (!valid) return;
  // heads 2w (cols c0..c0+7) and 2w+1 (cols c0+8..c0+15)
  float s1a = 0.f, s2a = 0.f, s1b = 0.f, s2b = 0.f;
#pragma unroll
  for (int cc = 0; cc < 8; ++cc) {
    s1a = fmaf(acc[cc], asrc[c0 + cc], s1a);
    s2a = fmaf(acc[cc], adst[c0 + cc], s2a);
    s1b = fmaf(acc[8 + cc], asrc[c0 + 8 + cc], s1b);
    s2b = fmaf(acc[8 + cc], adst[c0 + 8 + cc], s2b);
  }
  float2* al2 = (float2*)al;
  al2[(size_t)row * 8 + w] = {s1a, s1b};          // al[row][2w], al[row][2w+1]
  al2[(size_t)row * 8 + 4 + w] = {s2a, s2b};      // al[row][8+2w], al[row][8+2w+1]
  uint4* H4 = (uint4*)Hgb;
  uint4 o0 = {pack_bf16(acc[0], acc[1]), pack_bf16(acc[2], acc[3]),
              pack_bf16(acc[4], acc[5]), pack_bf16(acc[6], acc[7])};
  uint4 o1 = {pack_bf16(acc[8], acc[9]), pack_bf16(acc[10], acc[11]),
              pack_bf16(acc[12], acc[13]), pack_bf16(acc[14], acc[15])};
  H4[(size_t)row * 8 + w * 2] = o0;
  H4[(size_t)row * 8 + w * 2 + 1] = o1;
}

// ------------------------------ aggregations -------------------------------

enum { MODE_RW1 = 0, MODE_RW = 1, MODE_G0 = 2, MODE_GR = 3, MODE_GD = 4 };

template <int MODE>
__global__ __launch_bounds__(256) void k_agg(
    const int* __restrict__ off, const int* __restrict__ idx,
    const float* __restrict__ Hf, const u32* __restrict__ Hb,
    const float* __restrict__ dis, const float* __restrict__ bias,
    float* __restrict__ R, float* __restrict__ Xf, u32* __restrict__ Xb,
    int n) {
  int lane = threadIdx.x & 63;
  int d = blockIdx.x * 4 + (threadIdx.x >> 6);
  if (d >= n) return;
  int rg = lane >> 3, cg = lane & 7;
  int beg = off[d], end = off[d + 1];
  float acc[8];
#pragma unroll
  for (int i = 0; i < 8; ++i) acc[i] = 0.f;
  for (int base = beg; base < end; base += 64) {
    int cnt = end - base;
    if (cnt > 64) cnt = 64;
    int sidx = (lane < cnt) ? idx[base + lane] : -1;
    int nIter = (cnt + 7) >> 3;
    for (int j = 0; j < nIter; ++j) {
      int s = __shfl(sidx, j * 8 + rg, 64);
      if (s >= 0) {
        if (MODE == MODE_RW1) {
          const float4* p = (const float4*)Hf + ((size_t)s * 16 + cg * 2);
          float4 x = p[0], y = p[1];
          acc[0] += x.x; acc[1] += x.y; acc[2] += x.z; acc[3] += x.w;
          acc[4] += y.x; acc[5] += y.y; acc[6] += y.z; acc[7] += y.w;
        } else {
          uint4 w = ((const uint4*)Hb)[(size_t)s * 8 + cg];
          acc[0] += bf_lo(w.x); acc[1] += bf_hi(w.x);
          acc[2] += bf_lo(w.y); acc[3] += bf_hi(w.y);
          acc[4] += bf_lo(w.z); acc[5] += bf_hi(w.z);
          acc[6] += bf_lo(w.w); acc[7] += bf_hi(w.w);
        }
      }
    }
  }
#pragma unroll
  for (int m = 8; m < 64; m <<= 1)
#pragma unroll
    for (int i = 0; i < 8; ++i) acc[i] += __shfl_xor(acc[i], m, 64);
  if (rg != 0) return;
  if (MODE == MODE_RW1 || MODE == MODE_RW) {
    uint4 o = {pack_bf16(acc[0], acc[1]), pack_bf16(acc[2], acc[3]),
               pack_bf16(acc[4], acc[5]), pack_bf16(acc[6], acc[7])};
    ((uint4*)Xb)[(size_t)d * 8 + cg] = o;
    return;
  }
  float ddv = dis[d];
  uint4 hw = ((const uint4*)Hb)[(size_t)d * 8 + cg];
  float hs[8] = {bf_lo(hw.x), bf_hi(hw.x), bf_lo(hw.y), bf_hi(hw.y),
                 bf_lo(hw.z), bf_hi(hw.z), bf_lo(hw.w), bf_hi(hw.w)};
  float4 b0 = ((const float4*)bias)[cg * 2];
  float4 b1 = ((const float4*)bias)[cg * 2 + 1];
  float bv[8] = {b0.x, b0.y, b0.z, b0.w, b1.x, b1.y, b1.z, b1.w};
  float v[8];
#pragma unroll
  for (int i = 0; i < 8; ++i) v[i] = ddv * (acc[i] + hs[i]) + bv[i];
  float4* X4 = (float4*)Xf;
  size_t o0 = (size_t)d * 16 + cg * 2;
  if (MODE == MODE_GR) {
    float4* R4 = (float4*)R;
    float4 r0 = R4[o0], r1 = R4[o0 + 1];
    v[0] += r0.x; v[1] += r0.y; v[2] += r0.z; v[3] += r0.w;
    v[4] += r1.x; v[5] += r1.y; v[6] += r1.z; v[7] += r1.w;
    R4[o0] = {v[0], v[1], v[2], v[3]};
    R4[o0 + 1] = {v[4], v[5], v[6], v[7]};
    X4[o0] = {fmaxf(v[0], 0.f), fmaxf(v[1], 0.f), fmaxf(v[2], 0.f), fmaxf(v[3], 0.f)};
    X4[o0 + 1] = {fmaxf(v[4], 0.f), fmaxf(v[5], 0.f), fmaxf(v[6], 0.f), fmaxf(v[7], 0.f)};
  } else if (MODE == MODE_GD) {
    float4 x0 = X4[o0], x1 = X4[o0 + 1];
    X4[o0] = {x0.x + v[0], x0.y + v[1], x0.z + v[2], x0.w + v[3]};
    X4[o0 + 1] = {x1.x + v[4], x1.y + v[5], x1.z + v[6], x1.w + v[7]};
  } else {  // MODE_G0
    X4[o0] = {fmaxf(v[0], 0.f), fmaxf(v[1], 0.f), fmaxf(v[2], 0.f), fmaxf(v[3], 0.f)};
    X4[o0 + 1] = {fmaxf(v[4], 0.f), fmaxf(v[5], 0.f), fmaxf(v[6], 0.f), fmaxf(v[7], 0.f)};
  }
}

__global__ __launch_bounds__(256) void k_gat_agg(
    const int* __restrict__ off, const int* __restrict__ idx,
    const u32* __restrict__ Hgb, const float* __restrict__ al,
    const float* __restrict__ bias, float* __restrict__ X,
    float* __restrict__ R, int n) {
  int lane = threadIdx.x & 63;
  int d = blockIdx.x * 4 + (threadIdx.x >> 6);
  if (d >= n) return;
  int rg = lane >> 3, cg = lane & 7;
  float ald = al[(size_t)d * 16 + 8 + cg];
  float eself = lrelu(al[(size_t)d * 16 + cg] + ald);
  int beg = off[d], end = off[d + 1];
  float m = eself;
  for (int base = beg; base < end; base += 64) {
    int cnt = end - base;
    if (cnt > 64) cnt = 64;
    int sidx = (lane < cnt) ? idx[base + lane] : -1;
    int nIter = (cnt + 7) >> 3;
    for (int j = 0; j < nIter; ++j) {
      int s = __shfl(sidx, j * 8 + rg, 64);
      if (s >= 0) m = fmaxf(m, lrelu(al[(size_t)s * 16 + cg] + ald));
    }
  }
#pragma unroll
  for (int mm = 8; mm < 64; mm <<= 1) m = fmaxf(m, __shfl_xor(m, mm, 64));
  float denom = 0.f;
  float acc[8];
#pragma unroll
  for (int i = 0; i < 8; ++i) acc[i] = 0.f;
  for (int base = beg; base < end; base += 64) {
    int cnt = end - base;
    if (cnt > 64) cnt = 64;
    int sidx = (lane < cnt) ? idx[base + lane] : -1;
    int nIter = (cnt + 7) >> 3;
    for (int j = 0; j < nIter; ++j) {
      int s = __shfl(sidx, j * 8 + rg, 64);
      if (s >= 0) {
        float p = __expf(lrelu(al[(size_t)s * 16 + cg] + ald) - m);
        denom += p;
        uint4 w = ((const uint4*)Hgb)[(size_t)s * 8 + cg];
        acc[0] = fmaf(p, bf_lo(w.x), acc[0]); acc[1] = fmaf(p, bf_hi(w.x), acc[1]);
        acc[2] = fmaf(p, bf_lo(w.y), acc[2]); acc[3] = fmaf(p, bf_hi(w.y), acc[3]);
        acc[4] = fmaf(p, bf_lo(w.z), acc[4]); acc[5] = fmaf(p, bf_hi(w.z), acc[5]);
        acc[6] = fmaf(p, bf_lo(w.w), acc[6]); acc[7] = fmaf(p, bf_hi(w.w), acc[7]);
      }
    }
  }
#pragma unroll
  for (int mm = 8; mm < 64; mm <<= 1) {
#pragma unroll
    for (int i = 0; i < 8; ++i) acc[i] += __shfl_xor(acc[i], mm, 64);
    denom += __shfl_xor(denom, mm, 64);
  }
  if (rg != 0) return;
  float pself = __expf(eself - m);
  uint4 hw = ((const uint4*)Hgb)[(size_t)d * 8 + cg];
  float hs[8] = {bf_lo(hw.x), bf_hi(hw.x), bf_lo(hw.y), bf_hi(hw.y),
                 bf_lo(hw.z), bf_hi(hw.z), bf_lo(hw.w), bf_hi(hw.w)};
#pragma unroll
  for (int i = 0; i < 8; ++i) acc[i] = fmaf(pself, hs[i], acc[i]);
  denom += pself;
  float inv = 1.f / denom;
  float4 b0 = ((const float4*)bias)[cg * 2];
  float4 b1 = ((const float4*)bias)[cg * 2 + 1];
  float bv[8] = {b0.x, b0.y, b0.z, b0.w, b1.x, b1.y, b1.z, b1.w};
  float v[8];
#pragma unroll
  for (int i = 0; i < 8; ++i) v[i] = acc[i] * inv + bv[i];
  size_t o0 = (size_t)d * 16 + cg * 2;
  ((float4*)X)[o0] = {v[0], v[1], v[2], v[3]};
  ((float4*)X)[o0 + 1] = {v[4], v[5], v[6], v[7]};
  ((float4*)R)[o0] = {v[0], v[1], v[2], v[3]};
  ((float4*)R)[o0 + 1] = {v[4], v[5], v[6], v[7]};
}

// ------------------------------- final linear ------------------------------

__global__ __launch_bounds__(256) void k_fc(
    const float* __restrict__ X, const float* __restrict__ W,
    const float* __restrict__ b, float* __restrict__ out, int n) {
  __shared__ float Wl[640];
  __shared__ float bl[10];
  for (int i = threadIdx.x; i < 640; i += 256) Wl[i] = W[i];
  if (threadIdx.x < 10) bl[threadIdx.x] = b[threadIdx.x];
  __syncthreads();
  int r = blockIdx.x * blockDim.x + threadIdx.x;
  if (r >= n) return;
  float acc[10];
#pragma unroll
  for (int c = 0; c < 10; ++c) acc[c] = bl[c];
#pragma unroll
  for (int k = 0; k < 64; ++k) {
    float xv = X[(size_t)r * 64 + k];
#pragma unroll
    for (int c = 0; c < 10; ++c) acc[c] = fmaf(xv, Wl[k * 10 + c], acc[c]);
  }
#pragma unroll
  for (int c = 0; c < 10; ++c) out[(size_t)r * 10 + c] = acc[c];
}

// --------------------------------- launch ----------------------------------

extern "C" void kernel_launch(void* const* d_in, const int* in_sizes, int n_in,
                              void* d_out, int out_size, void* d_ws, size_t ws_size,
                              hipStream_t stream) {
  const float* x_in  = (const float*)d_in[0];
  const int*   ei    = (const int*)d_in[1];
  const float* gatW  = (const float*)d_in[2];
  const float* gatAs = (const float*)d_in[3];
  const float* gatAd = (const float*)d_in[4];
  const float* gatB  = (const float*)d_in[5];
  const float* gcnW  = (const float*)d_in[6];
  const float* gcnB  = (const float*)d_in[7];
  const float* fcW   = (const float*)d_in[8];
  const float* fcB   = (const float*)d_in[9];
  float* out = (float*)d_out;

  const int N = in_sizes[0] / 64;
  const int E = in_sizes[1] / 2;
  const int NB = (N + RNGB - 1) >> BSH;
  const int chunk = (E + GEB - 1) / GEB;

  char* ws = (char*)d_ws;
  size_t o = 0;
  auto alloc = [&](size_t bytes) -> char* {
    char* p = ws + o;
    o = (o + bytes + 255) & ~(size_t)255;
    return p;
  };
  int* offA    = (int*)alloc((size_t)(N + 1) * 4);
  int* offB    = (int*)alloc((size_t)(N + 1) * 4);
  float* dis   = (float*)alloc((size_t)N * 4);
  int* idxA    = (int*)alloc((size_t)E * 4);
  int* idxB    = (int*)alloc((size_t)E * 4);
  int2* pairsA = (int2*)alloc((size_t)E * 8);
  int2* pairsB = (int2*)alloc((size_t)E * 8);
  int* gHistA  = (int*)alloc((size_t)GEB * NB * 4);
  int* gHistB  = (int*)alloc((size_t)GEB * NB * 4);
  int* totA    = (int*)alloc((size_t)NB * 4);
  int* totB    = (int*)alloc((size_t)NB * 4);
  int* baseA   = (int*)alloc((size_t)NB * 4);
  int* baseB   = (int*)alloc((size_t)NB * 4);
  float* al    = (float*)alloc((size_t)N * 16 * 4);
  u32* B0      = (u32*)alloc((size_t)N * 32 * 4);
  u32* B1      = (u32*)alloc((size_t)N * 32 * 4);
  float* X     = (float*)alloc((size_t)N * 64 * 4);
  float* R     = (float*)alloc((size_t)N * 64 * 4);

  int nbN = (N + 255) / 256;
  int nbAgg = (N + 3) / 4;
  int nbG = (N + 63) / 64;

  // ---- CSR build: bucketed counting sort ----
  k_hist<<<GEB, 256, 0, stream>>>(ei, E, NB, chunk, gHistA, gHistB);
  k_colscan<<<NB, GEB, 0, stream>>>(gHistA, totA, NB);
  k_colscan<<<NB, GEB, 0, stream>>>(gHistB, totB, NB);
  k_bscan<<<1, 1024, 0, stream>>>(totA, totB, baseA, baseB, offA, offB, NB, N, E);
  k_scatter<<<GEB, 256, 0, stream>>>(ei, E, NB, chunk, gHistA, gHistB,
                                     baseA, baseB, pairsA, pairsB);
  k_bucket<0><<<NB, 256, 0, stream>>>(pairsA, baseA, totA, offA, idxA, nullptr, N);
  k_bucket<1><<<NB, 256, 0, stream>>>(pairsB, baseB, totB, offB, idxB, dis, N);

  // ---- random walk: 5 steps (fp32 in -> bf16 ping-pong) ----
  k_agg<MODE_RW1><<<nbAgg, 256, 0, stream>>>(offA, idxA, x_in, nullptr, nullptr, nullptr, nullptr, nullptr, B0, N);
  k_agg<MODE_RW><<<nbAgg, 256, 0, stream>>>(offA, idxA, nullptr, B0, nullptr, nullptr, nullptr, nullptr, B1, N);
  k_agg<MODE_RW><<<nbAgg, 256, 0, stream>>>(offA, idxA, nullptr, B1, nullptr, nullptr, nullptr, nullptr, B0, N);
  k_agg<MODE_RW><<<nbAgg, 256, 0, stream>>>(offA, idxA, nullptr, B0, nullptr, nullptr, nullptr, nullptr, B1, N);
  k_agg<MODE_RW><<<nbAgg, 256, 0, stream>>>(offA, idxA, nullptr, B1, nullptr, nullptr, nullptr, nullptr, B0, N);

  // ---- GAT ----
  k_gat_gemm<<<nbG, 256, 0, stream>>>(B0, gatW, gatAs, gatAd, B1, al, N);
  k_gat_agg<<<nbAgg, 256, 0, stream>>>(offB, idxB, B1, al, gatB, X, R, N);

  // ---- residual GCN ----
  for (int i = 0; i < 12; ++i) {
    k_gemm64<<<nbG, 256, 0, stream>>>(X, gcnW + i * 4096, dis, B0, N);
    if (i == 0)
      k_agg<MODE_G0><<<nbAgg, 256, 0, stream>>>(offB, idxB, nullptr, B0, dis, gcnB + i * 64, nullptr, X, nullptr, N);
    else
      k_agg<MODE_GR><<<nbAgg, 256, 0, stream>>>(offB, idxB, nullptr, B0, dis, gcnB + i * 64, R, X, nullptr, N);
    if (i < 11) {
      int j = (i == 0) ? 11 : i - 1;
      k_gemm64<<<nbG, 256, 0, stream>>>(X, gcnW + j * 4096, dis, B0, N);
      k_agg<MODE_GD><<<nbAgg, 256, 0, stream>>>(offB, idxB, nullptr, B0, dis, gcnB + j * 64, nullptr, X, nullptr, N);
    }
  }

  // ---- final linear ----
  k_fc<<<nbN, 256, 0, stream>>>(X, fcW, fcB, out, N);
}

// Round 6
// 1966.726 us; speedup vs baseline: 1.5670x; 1.5670x over previous
//
#include <hip/hip_runtime.h>

// ---------------------------------------------------------------------------
// LRA_GNN: random-walk -> 8-head GAT -> 12-layer residual GCN -> FC.
// Round 6: GEMMs stage the X tile in LDS once per block (coalesced float4,
// +1 pad -> conflict-free reads); wave w computes cols [16w,16w+16) with
// acc[16] (no AGPR spill), W via wave-uniform scalar loads. Fixes round 5's
// 4x redundant X fetch. CSR sort build + bf16 gather tables unchanged.
// ---------------------------------------------------------------------------

typedef unsigned int u32;

#define BSH 7              // bucket shift: 128 nodes per bucket
#define RNGB 128           // nodes per bucket
#define GEB 256            // edge-pass blocks

__device__ __forceinline__ float lrelu(float v) { return v > 0.f ? v : 0.2f * v; }
__device__ __forceinline__ float bf_lo(u32 w) { return __uint_as_float(w << 16); }
__device__ __forceinline__ float bf_hi(u32 w) { return __uint_as_float(w & 0xffff0000u); }
__device__ __forceinline__ u32 pack_bf16(float a, float b) {
  u32 ua = __float_as_uint(a); ua = ua + 0x7fffu + ((ua >> 16) & 1u);
  u32 ub = __float_as_uint(b); ub = ub + 0x7fffu + ((ub >> 16) & 1u);
  return (ua >> 16) | (ub & 0xffff0000u);
}

// --------------------- CSR build via bucketed counting sort ----------------

__global__ __launch_bounds__(256) void k_hist(
    const int* __restrict__ ei, int E, int NB, int chunk,
    int* __restrict__ gHistA, int* __restrict__ gHistB) {
  __shared__ int hA[1024], hB[1024];
  for (int i = threadIdx.x; i < NB; i += 256) { hA[i] = 0; hB[i] = 0; }
  __syncthreads();
  int e0 = blockIdx.x * chunk;
  int e1 = min(E, e0 + chunk);
  for (int e = e0 + threadIdx.x; e < e1; e += 256) {
    int s = ei[e], d = ei[E + e];
    atomicAdd(&hA[s >> BSH], 1);
    atomicAdd(&hB[d >> BSH], 1);
  }
  __syncthreads();
  for (int i = threadIdx.x; i < NB; i += 256) {
    gHistA[blockIdx.x * NB + i] = hA[i];
    gHistB[blockIdx.x * NB + i] = hB[i];
  }
}

__global__ __launch_bounds__(256) void k_colscan(
    int* __restrict__ gHist, int* __restrict__ tot, int NB) {
  __shared__ int s[GEB];
  int b = blockIdx.x;
  int t = threadIdx.x;
  int v = gHist[t * NB + b];
  s[t] = v;
  __syncthreads();
  for (int d = 1; d < GEB; d <<= 1) {
    int u = (t >= d) ? s[t - d] : 0;
    __syncthreads();
    s[t] += u;
    __syncthreads();
  }
  gHist[t * NB + b] = s[t] - v;
  if (t == GEB - 1) tot[b] = s[t];
}

__global__ __launch_bounds__(1024) void k_bscan(
    const int* __restrict__ totA, const int* __restrict__ totB,
    int* __restrict__ baseA, int* __restrict__ baseB,
    int* __restrict__ offA, int* __restrict__ offB, int NB, int N, int E) {
  __shared__ int sa[1024], sb[1024];
  int t = threadIdx.x;
  int va = (t < NB) ? totA[t] : 0;
  int vb = (t < NB) ? totB[t] : 0;
  sa[t] = va; sb[t] = vb;
  __syncthreads();
  for (int d = 1; d < 1024; d <<= 1) {
    int ua = (t >= d) ? sa[t - d] : 0;
    int ub = (t >= d) ? sb[t - d] : 0;
    __syncthreads();
    sa[t] += ua; sb[t] += ub;
    __syncthreads();
  }
  if (t < NB) { baseA[t] = sa[t] - va; baseB[t] = sb[t] - vb; }
  if (t == 0) { offA[N] = E; offB[N] = E; }
}

__global__ __launch_bounds__(256) void k_scatter(
    const int* __restrict__ ei, int E, int NB, int chunk,
    const int* __restrict__ gHistA, const int* __restrict__ gHistB,
    const int* __restrict__ baseA, const int* __restrict__ baseB,
    int2* __restrict__ pairsA, int2* __restrict__ pairsB) {
  __shared__ int cA[1024], cB[1024];
  int g = blockIdx.x;
  for (int i = threadIdx.x; i < NB; i += 256) {
    cA[i] = baseA[i] + gHistA[g * NB + i];
    cB[i] = baseB[i] + gHistB[g * NB + i];
  }
  __syncthreads();
  int e0 = g * chunk;
  int e1 = min(E, e0 + chunk);
  for (int e = e0 + threadIdx.x; e < e1; e += 256) {
    int s = ei[e], d = ei[E + e];
    int pa = atomicAdd(&cA[s >> BSH], 1);
    pairsA[pa] = {s, d};
    int pb = atomicAdd(&cB[d >> BSH], 1);
    pairsB[pb] = {s, d};
  }
}

template <int KEY>
__global__ __launch_bounds__(256) void k_bucket(
    const int2* __restrict__ pairs, const int* __restrict__ base,
    const int* __restrict__ tot, int* __restrict__ off,
    int* __restrict__ idx, float* __restrict__ dis, int N) {
  __shared__ int cnt[RNGB], pfx[RNGB];
  int b = blockIdx.x;
  int node0 = b << BSH;
  int rng = min(RNGB, N - node0);
  int bstart = base[b], bcount = tot[b];
  for (int i = threadIdx.x; i < rng; i += 256) cnt[i] = 0;
  __syncthreads();
  for (int i = threadIdx.x; i < bcount; i += 256) {
    int2 p = pairs[bstart + i];
    int loc = (KEY == 0 ? p.x : p.y) - node0;
    atomicAdd(&cnt[loc], 1);
  }
  __syncthreads();
  if (threadIdx.x == 0) {
    int run = 0;
    for (int i = 0; i < rng; ++i) { pfx[i] = run; run += cnt[i]; }
  }
  __syncthreads();
  for (int i = threadIdx.x; i < rng; i += 256) {
    off[node0 + i] = bstart + pfx[i];
    if (KEY == 1) dis[node0 + i] = rsqrtf((float)(cnt[i] + 1));
  }
  __syncthreads();
  for (int i = threadIdx.x; i < bcount; i += 256) {
    int2 p = pairs[bstart + i];
    int loc = (KEY == 0 ? p.x : p.y) - node0;
    int pos = bstart + atomicAdd(&pfx[loc], 1);
    idx[pos] = (KEY == 0 ? p.y : p.x);
  }
}

// --------------------------------- GEMMs -----------------------------------

// Block = 64 rows staged once in LDS (pad 65 -> 2-way free). Wave w computes
// cols [16w,16w+16); lane = row; W via wave-uniform scalar loads.
__global__ __launch_bounds__(256) void k_gemm64(
    const float* __restrict__ X, const float* __restrict__ W,
    const float* __restrict__ dis, u32* __restrict__ Hb, int n) {
  __shared__ float Xs[64 * 65];
  int row0 = blockIdx.x * 64;
  for (int t = threadIdx.x; t < 1024; t += 256) {
    int r = t >> 4, k4 = t & 15;
    int row = row0 + r;
    float4 v = (row < n) ? ((const float4*)X)[(size_t)row * 16 + k4]
                         : float4{0.f, 0.f, 0.f, 0.f};
    float* dst = &Xs[r * 65 + k4 * 4];
    dst[0] = v.x; dst[1] = v.y; dst[2] = v.z; dst[3] = v.w;
  }
  __syncthreads();
  int lane = threadIdx.x & 63;
  int w = __builtin_amdgcn_readfirstlane(threadIdx.x >> 6);
  int c0 = w * 16;
  int row = row0 + lane;
  float acc[16];
#pragma unroll
  for (int c = 0; c < 16; ++c) acc[c] = 0.f;
#pragma unroll 4
  for (int k = 0; k < 64; ++k) {
    float xk = Xs[lane * 65 + k];
#pragma unroll
    for (int c = 0; c < 16; ++c)
      acc[c] = fmaf(xk, W[k * 64 + c0 + c], acc[c]);
  }
  if (row >= n) return;
  float sc = dis[row];
  uint4* H4 = (uint4*)Hb;
  uint4 o0 = {pack_bf16(acc[0] * sc, acc[1] * sc), pack_bf16(acc[2] * sc, acc[3] * sc),
              pack_bf16(acc[4] * sc, acc[5] * sc), pack_bf16(acc[6] * sc, acc[7] * sc)};
  uint4 o1 = {pack_bf16(acc[8] * sc, acc[9] * sc), pack_bf16(acc[10] * sc, acc[11] * sc),
              pack_bf16(acc[12] * sc, acc[13] * sc), pack_bf16(acc[14] * sc, acc[15] * sc)};
  H4[(size_t)row * 8 + w * 2] = o0;
  H4[(size_t)row * 8 + w * 2 + 1] = o1;
}

// GAT projection from bf16 X (unpacked to fp32 during LDS staging).
// Wave w owns cols [16w,16w+16) = heads 2w,2w+1.
__global__ __launch_bounds__(256) void k_gat_gemm(
    const u32* __restrict__ Xb, const float* __restrict__ W,
    const float* __restrict__ asrc, const float* __restrict__ adst,
    u32* __restrict__ Hgb, float* __restrict__ al, int n) {
  __shared__ float Xs[64 * 65];
  int row0 = blockIdx.x * 64;
  for (int t = threadIdx.x; t < 512; t += 256) {
    int r = t >> 3, k8 = t & 7;
    int row = row0 + r;
    uint4 xw = (row < n) ? ((const uint4*)Xb)[(size_t)row * 8 + k8]
                         : uint4{0u, 0u, 0u, 0u};
    float* dst = &Xs[r * 65 + k8 * 8];
    dst[0] = bf_lo(xw.x); dst[1] = bf_hi(xw.x);
    dst[2] = bf_lo(xw.y); dst[3] = bf_hi(xw.y);
    dst[4] = bf_lo(xw.z); dst[5] = bf_hi(xw.z);
    dst[6] = bf_lo(xw.w); dst[7] = bf_hi(xw.w);
  }
  __syncthreads();
  int lane = threadIdx.x & 63;
  int w = __builtin_amdgcn_readfirstlane(threadIdx.x >> 6);
  int c0 = w * 16;
  int row = row0 + lane;
  float acc[16];
#pragma unroll
  for (int c = 0; c < 16; ++c) acc[c] = 0.f;
#pragma unroll 4
  for (int k = 0; k < 64; ++k) {
    float xk = Xs[lane * 65 + k];
#pragma unroll
    for (int c = 0; c < 16; ++c) {
      int gc = c0 + c;
      acc[c] = fmaf(xk, W[(gc >> 3) * 512 + k * 8 + (gc & 7)], acc[c]);
    }
  }
  if (row >= n) return;
  float s1a = 0.f, s2a = 0.f, s1b = 0.f, s2b = 0.f;
#pragma unroll
  for (int cc = 0; cc < 8; ++cc) {
    s1a = fmaf(acc[cc], asrc[c0 + cc], s1a);
    s2a = fmaf(acc[cc], adst[c0 + cc], s2a);
    s1b = fmaf(acc[8 + cc], asrc[c0 + 8 + cc], s1b);
    s2b = fmaf(acc[8 + cc], adst[c0 + 8 + cc], s2b);
  }
  float2* al2 = (float2*)al;
  al2[(size_t)row * 8 + w] = {s1a, s1b};
  al2[(size_t)row * 8 + 4 + w] = {s2a, s2b};
  uint4* H4 = (uint4*)Hgb;
  uint4 o0 = {pack_bf16(acc[0], acc[1]), pack_bf16(acc[2], acc[3]),
              pack_bf16(acc[4], acc[5]), pack_bf16(acc[6], acc[7])};
  uint4 o1 = {pack_bf16(acc[8], acc[9]), pack_bf16(acc[10], acc[11]),
              pack_bf16(acc[12], acc[13]), pack_bf16(acc[14], acc[15])};
  H4[(size_t)row * 8 + w * 2] = o0;
  H4[(size_t)row * 8 + w * 2 + 1] = o1;
}

// ------------------------------ aggregations -------------------------------

enum { MODE_RW1 = 0, MODE_RW = 1, MODE_G0 = 2, MODE_GR = 3, MODE_GD = 4 };

template <int MODE>
__global__ __launch_bounds__(256) void k_agg(
    const int* __restrict__ off, const int* __restrict__ idx,
    const float* __restrict__ Hf, const u32* __restrict__ Hb,
    const float* __restrict__ dis, const float* __restrict__ bias,
    float* __restrict__ R, float* __restrict__ Xf, u32* __restrict__ Xb,
    int n) {
  int lane = threadIdx.x & 63;
  int d = blockIdx.x * 4 + (threadIdx.x >> 6);
  if (d >= n) return;
  int rg = lane >> 3, cg = lane & 7;
  int beg = off[d], end = off[d + 1];
  float acc[8];
#pragma unroll
  for (int i = 0; i < 8; ++i) acc[i] = 0.f;
  for (int base = beg; base < end; base += 64) {
    int cnt = end - base;
    if (cnt > 64) cnt = 64;
    int sidx = (lane < cnt) ? idx[base + lane] : -1;
    int nIter = (cnt + 7) >> 3;
    for (int j = 0; j < nIter; ++j) {
      int s = __shfl(sidx, j * 8 + rg, 64);
      if (s >= 0) {
        if (MODE == MODE_RW1) {
          const float4* p = (const float4*)Hf + ((size_t)s * 16 + cg * 2);
          float4 x = p[0], y = p[1];
          acc[0] += x.x; acc[1] += x.y; acc[2] += x.z; acc[3] += x.w;
          acc[4] += y.x; acc[5] += y.y; acc[6] += y.z; acc[7] += y.w;
        } else {
          uint4 w = ((const uint4*)Hb)[(size_t)s * 8 + cg];
          acc[0] += bf_lo(w.x); acc[1] += bf_hi(w.x);
          acc[2] += bf_lo(w.y); acc[3] += bf_hi(w.y);
          acc[4] += bf_lo(w.z); acc[5] += bf_hi(w.z);
          acc[6] += bf_lo(w.w); acc[7] += bf_hi(w.w);
        }
      }
    }
  }
#pragma unroll
  for (int m = 8; m < 64; m <<= 1)
#pragma unroll
    for (int i = 0; i < 8; ++i) acc[i] += __shfl_xor(acc[i], m, 64);
  if (rg != 0) return;
  if (MODE == MODE_RW1 || MODE == MODE_RW) {
    uint4 o = {pack_bf16(acc[0], acc[1]), pack_bf16(acc[2], acc[3]),
               pack_bf16(acc[4], acc[5]), pack_bf16(acc[6], acc[7])};
    ((uint4*)Xb)[(size_t)d * 8 + cg] = o;
    return;
  }
  float ddv = dis[d];
  uint4 hw = ((const uint4*)Hb)[(size_t)d * 8 + cg];
  float hs[8] = {bf_lo(hw.x), bf_hi(hw.x), bf_lo(hw.y), bf_hi(hw.y),
                 bf_lo(hw.z), bf_hi(hw.z), bf_lo(hw.w), bf_hi(hw.w)};
  float4 b0 = ((const float4*)bias)[cg * 2];
  float4 b1 = ((const float4*)bias)[cg * 2 + 1];
  float bv[8] = {b0.x, b0.y, b0.z, b0.w, b1.x, b1.y, b1.z, b1.w};
  float v[8];
#pragma unroll
  for (int i = 0; i < 8; ++i) v[i] = ddv * (acc[i] + hs[i]) + bv[i];
  float4* X4 = (float4*)Xf;
  size_t o0 = (size_t)d * 16 + cg * 2;
  if (MODE == MODE_GR) {
    float4* R4 = (float4*)R;
    float4 r0 = R4[o0], r1 = R4[o0 + 1];
    v[0] += r0.x; v[1] += r0.y; v[2] += r0.z; v[3] += r0.w;
    v[4] += r1.x; v[5] += r1.y; v[6] += r1.z; v[7] += r1.w;
    R4[o0] = {v[0], v[1], v[2], v[3]};
    R4[o0 + 1] = {v[4], v[5], v[6], v[7]};
    X4[o0] = {fmaxf(v[0], 0.f), fmaxf(v[1], 0.f), fmaxf(v[2], 0.f), fmaxf(v[3], 0.f)};
    X4[o0 + 1] = {fmaxf(v[4], 0.f), fmaxf(v[5], 0.f), fmaxf(v[6], 0.f), fmaxf(v[7], 0.f)};
  } else if (MODE == MODE_GD) {
    float4 x0 = X4[o0], x1 = X4[o0 + 1];
    X4[o0] = {x0.x + v[0], x0.y + v[1], x0.z + v[2], x0.w + v[3]};
    X4[o0 + 1] = {x1.x + v[4], x1.y + v[5], x1.z + v[6], x1.w + v[7]};
  } else {  // MODE_G0
    X4[o0] = {fmaxf(v[0], 0.f), fmaxf(v[1], 0.f), fmaxf(v[2], 0.f), fmaxf(v[3], 0.f)};
    X4[o0 + 1] = {fmaxf(v[4], 0.f), fmaxf(v[5], 0.f), fmaxf(v[6], 0.f), fmaxf(v[7], 0.f)};
  }
}

__global__ __launch_bounds__(256) void k_gat_agg(
    const int* __restrict__ off, const int* __restrict__ idx,
    const u32* __restrict__ Hgb, const float* __restrict__ al,
    const float* __restrict__ bias, float* __restrict__ X,
    float* __restrict__ R, int n) {
  int lane = threadIdx.x & 63;
  int d = blockIdx.x * 4 + (threadIdx.x >> 6);
  if (d >= n) return;
  int rg = lane >> 3, cg = lane & 7;
  float ald = al[(size_t)d * 16 + 8 + cg];
  float eself = lrelu(al[(size_t)d * 16 + cg] + ald);
  int beg = off[d], end = off[d + 1];
  float m = eself;
  for (int base = beg; base < end; base += 64) {
    int cnt = end - base;
    if (cnt > 64) cnt = 64;
    int sidx = (lane < cnt) ? idx[base + lane] : -1;
    int nIter = (cnt + 7) >> 3;
    for (int j = 0; j < nIter; ++j) {
      int s = __shfl(sidx, j * 8 + rg, 64);
      if (s >= 0) m = fmaxf(m, lrelu(al[(size_t)s * 16 + cg] + ald));
    }
  }
#pragma unroll
  for (int mm = 8; mm < 64; mm <<= 1) m = fmaxf(m, __shfl_xor(m, mm, 64));
  float denom = 0.f;
  float acc[8];
#pragma unroll
  for (int i = 0; i < 8; ++i) acc[i] = 0.f;
  for (int base = beg; base < end; base += 64) {
    int cnt = end - base;
    if (cnt > 64) cnt = 64;
    int sidx = (lane < cnt) ? idx[base + lane] : -1;
    int nIter = (cnt + 7) >> 3;
    for (int j = 0; j < nIter; ++j) {
      int s = __shfl(sidx, j * 8 + rg, 64);
      if (s >= 0) {
        float p = __expf(lrelu(al[(size_t)s * 16 + cg] + ald) - m);
        denom += p;
        uint4 w = ((const uint4*)Hgb)[(size_t)s * 8 + cg];
        acc[0] = fmaf(p, bf_lo(w.x), acc[0]); acc[1] = fmaf(p, bf_hi(w.x), acc[1]);
        acc[2] = fmaf(p, bf_lo(w.y), acc[2]); acc[3] = fmaf(p, bf_hi(w.y), acc[3]);
        acc[4] = fmaf(p, bf_lo(w.z), acc[4]); acc[5] = fmaf(p, bf_hi(w.z), acc[5]);
        acc[6] = fmaf(p, bf_lo(w.w), acc[6]); acc[7] = fmaf(p, bf_hi(w.w), acc[7]);
      }
    }
  }
#pragma unroll
  for (int mm = 8; mm < 64; mm <<= 1) {
#pragma unroll
    for (int i = 0; i < 8; ++i) acc[i] += __shfl_xor(acc[i], mm, 64);
    denom += __shfl_xor(denom, mm, 64);
  }
  if (rg != 0) return;
  float pself = __expf(eself - m);
  uint4 hw = ((const uint4*)Hgb)[(size_t)d * 8 + cg];
  float hs[8] = {bf_lo(hw.x), bf_hi(hw.x), bf_lo(hw.y), bf_hi(hw.y),
                 bf_lo(hw.z), bf_hi(hw.z), bf_lo(hw.w), bf_hi(hw.w)};
#pragma unroll
  for (int i = 0; i < 8; ++i) acc[i] = fmaf(pself, hs[i], acc[i]);
  denom += pself;
  float inv = 1.f / denom;
  float4 b0 = ((const float4*)bias)[cg * 2];
  float4 b1 = ((const float4*)bias)[cg * 2 + 1];
  float bv[8] = {b0.x, b0.y, b0.z, b0.w, b1.x, b1.y, b1.z, b1.w};
  float v[8];
#pragma unroll
  for (int i = 0; i < 8; ++i) v[i] = acc[i] * inv + bv[i];
  size_t o0 = (size_t)d * 16 + cg * 2;
  ((float4*)X)[o0] = {v[0], v[1], v[2], v[3]};
  ((float4*)X)[o0 + 1] = {v[4], v[5], v[6], v[7]};
  ((float4*)R)[o0] = {v[0], v[1], v[2], v[3]};
  ((float4*)R)[o0 + 1] = {v[4], v[5], v[6], v[7]};
}

// ------------------------------- final linear ------------------------------

__global__ __launch_bounds__(256) void k_fc(
    const float* __restrict__ X, const float* __restrict__ W,
    const float* __restrict__ b, float* __restrict__ out, int n) {
  __shared__ float Wl[640];
  __shared__ float bl[10];
  for (int i = threadIdx.x; i < 640; i += 256) Wl[i] = W[i];
  if (threadIdx.x < 10) bl[threadIdx.x] = b[threadIdx.x];
  __syncthreads();
  int r = blockIdx.x * blockDim.x + threadIdx.x;
  if (r >= n) return;
  float acc[10];
#pragma unroll
  for (int c = 0; c < 10; ++c) acc[c] = bl[c];
#pragma unroll
  for (int k = 0; k < 64; ++k) {
    float xv = X[(size_t)r * 64 + k];
#pragma unroll
    for (int c = 0; c < 10; ++c) acc[c] = fmaf(xv, Wl[k * 10 + c], acc[c]);
  }
#pragma unroll
  for (int c = 0; c < 10; ++c) out[(size_t)r * 10 + c] = acc[c];
}

// --------------------------------- launch ----------------------------------

extern "C" void kernel_launch(void* const* d_in, const int* in_sizes, int n_in,
                              void* d_out, int out_size, void* d_ws, size_t ws_size,
                              hipStream_t stream) {
  const float* x_in  = (const float*)d_in[0];
  const int*   ei    = (const int*)d_in[1];
  const float* gatW  = (const float*)d_in[2];
  const float* gatAs = (const float*)d_in[3];
  const float* gatAd = (const float*)d_in[4];
  const float* gatB  = (const float*)d_in[5];
  const float* gcnW  = (const float*)d_in[6];
  const float* gcnB  = (const float*)d_in[7];
  const float* fcW   = (const float*)d_in[8];
  const float* fcB   = (const float*)d_in[9];
  float* out = (float*)d_out;

  const int N = in_sizes[0] / 64;
  const int E = in_sizes[1] / 2;
  const int NB = (N + RNGB - 1) >> BSH;
  const int chunk = (E + GEB - 1) / GEB;

  char* ws = (char*)d_ws;
  size_t o = 0;
  auto alloc = [&](size_t bytes) -> char* {
    char* p = ws + o;
    o = (o + bytes + 255) & ~(size_t)255;
    return p;
  };
  int* offA    = (int*)alloc((size_t)(N + 1) * 4);
  int* offB    = (int*)alloc((size_t)(N + 1) * 4);
  float* dis   = (float*)alloc((size_t)N * 4);
  int* idxA    = (int*)alloc((size_t)E * 4);
  int* idxB    = (int*)alloc((size_t)E * 4);
  int2* pairsA = (int2*)alloc((size_t)E * 8);
  int2* pairsB = (int2*)alloc((size_t)E * 8);
  int* gHistA  = (int*)alloc((size_t)GEB * NB * 4);
  int* gHistB  = (int*)alloc((size_t)GEB * NB * 4);
  int* totA    = (int*)alloc((size_t)NB * 4);
  int* totB    = (int*)alloc((size_t)NB * 4);
  int* baseA   = (int*)alloc((size_t)NB * 4);
  int* baseB   = (int*)alloc((size_t)NB * 4);
  float* al    = (float*)alloc((size_t)N * 16 * 4);
  u32* B0      = (u32*)alloc((size_t)N * 32 * 4);
  u32* B1      = (u32*)alloc((size_t)N * 32 * 4);
  float* X     = (float*)alloc((size_t)N * 64 * 4);
  float* R     = (float*)alloc((size_t)N * 64 * 4);

  int nbN = (N + 255) / 256;
  int nbAgg = (N + 3) / 4;
  int nbG = (N + 63) / 64;

  // ---- CSR build: bucketed counting sort ----
  k_hist<<<GEB, 256, 0, stream>>>(ei, E, NB, chunk, gHistA, gHistB);
  k_colscan<<<NB, GEB, 0, stream>>>(gHistA, totA, NB);
  k_colscan<<<NB, GEB, 0, stream>>>(gHistB, totB, NB);
  k_bscan<<<1, 1024, 0, stream>>>(totA, totB, baseA, baseB, offA, offB, NB, N, E);
  k_scatter<<<GEB, 256, 0, stream>>>(ei, E, NB, chunk, gHistA, gHistB,
                                     baseA, baseB, pairsA, pairsB);
  k_bucket<0><<<NB, 256, 0, stream>>>(pairsA, baseA, totA, offA, idxA, nullptr, N);
  k_bucket<1><<<NB, 256, 0, stream>>>(pairsB, baseB, totB, offB, idxB, dis, N);

  // ---- random walk: 5 steps (fp32 in -> bf16 ping-pong) ----
  k_agg<MODE_RW1><<<nbAgg, 256, 0, stream>>>(offA, idxA, x_in, nullptr, nullptr, nullptr, nullptr, nullptr, B0, N);
  k_agg<MODE_RW><<<nbAgg, 256, 0, stream>>>(offA, idxA, nullptr, B0, nullptr, nullptr, nullptr, nullptr, B1, N);
  k_agg<MODE_RW><<<nbAgg, 256, 0, stream>>>(offA, idxA, nullptr, B1, nullptr, nullptr, nullptr, nullptr, B0, N);
  k_agg<MODE_RW><<<nbAgg, 256, 0, stream>>>(offA, idxA, nullptr, B0, nullptr, nullptr, nullptr, nullptr, B1, N);
  k_agg<MODE_RW><<<nbAgg, 256, 0, stream>>>(offA, idxA, nullptr, B1, nullptr, nullptr, nullptr, nullptr, B0, N);

  // ---- GAT ----
  k_gat_gemm<<<nbG, 256, 0, stream>>>(B0, gatW, gatAs, gatAd, B1, al, N);
  k_gat_agg<<<nbAgg, 256, 0, stream>>>(offB, idxB, B1, al, gatB, X, R, N);

  // ---- residual GCN ----
  for (int i = 0; i < 12; ++i) {
    k_gemm64<<<nbG, 256, 0, stream>>>(X, gcnW + i * 4096, dis, B0, N);
    if (i == 0)
      k_agg<MODE_G0><<<nbAgg, 256, 0, stream>>>(offB, idxB, nullptr, B0, dis, gcnB + i * 64, nullptr, X, nullptr, N);
    else
      k_agg<MODE_GR><<<nbAgg, 256, 0, stream>>>(offB, idxB, nullptr, B0, dis, gcnB + i * 64, R, X, nullptr, N);
    if (i < 11) {
      int j = (i == 0) ? 11 : i - 1;
      k_gemm64<<<nbG, 256, 0, stream>>>(X, gcnW + j * 4096, dis, B0, N);
      k_agg<MODE_GD><<<nbAgg, 256, 0, stream>>>(offB, idxB, nullptr, B0, dis, gcnB + j * 64, nullptr, X, nullptr, N);
    }
  }

  // ---- final linear ----
  k_fc<<<nbN, 256, 0, stream>>>(X, fcW, fcB, out, N);
}

// Round 8
// 1842.860 us; speedup vs baseline: 1.6723x; 1.0672x over previous
//
#include <hip/hip_runtime.h>

// ---------------------------------------------------------------------------
// LRA_GNN: random-walk -> 8-head GAT -> 12-layer residual GCN -> FC.
// Round 8 (= round 7 fixed): aggregation gathers software-pipelined 2-deep
// (2-4 loads in flight per wave vs 1) — aggs were latency-bound at MLP=1
// (3.07 TB/s == 24 waves/CU x 128B / 600cy). The ACC8 macro was replaced by
// an inline function (macro param 'w' collided with the '.w' member token).
// ---------------------------------------------------------------------------

typedef unsigned int u32;

#define BSH 7              // bucket shift: 128 nodes per bucket
#define RNGB 128           // nodes per bucket
#define GEB 256            // edge-pass blocks

__device__ __forceinline__ float lrelu(float v) { return v > 0.f ? v : 0.2f * v; }
__device__ __forceinline__ float bf_lo(u32 w) { return __uint_as_float(w << 16); }
__device__ __forceinline__ float bf_hi(u32 w) { return __uint_as_float(w & 0xffff0000u); }
__device__ __forceinline__ u32 pack_bf16(float a, float b) {
  u32 ua = __float_as_uint(a); ua = ua + 0x7fffu + ((ua >> 16) & 1u);
  u32 ub = __float_as_uint(b); ub = ub + 0x7fffu + ((ub >> 16) & 1u);
  return (ua >> 16) | (ub & 0xffff0000u);
}
__device__ __forceinline__ void acc8(float* acc, uint4 q) {
  acc[0] += bf_lo(q.x); acc[1] += bf_hi(q.x);
  acc[2] += bf_lo(q.y); acc[3] += bf_hi(q.y);
  acc[4] += bf_lo(q.z); acc[5] += bf_hi(q.z);
  acc[6] += bf_lo(q.w); acc[7] += bf_hi(q.w);
}
__device__ __forceinline__ void fma8(float* acc, float p, uint4 q) {
  acc[0] = fmaf(p, bf_lo(q.x), acc[0]); acc[1] = fmaf(p, bf_hi(q.x), acc[1]);
  acc[2] = fmaf(p, bf_lo(q.y), acc[2]); acc[3] = fmaf(p, bf_hi(q.y), acc[3]);
  acc[4] = fmaf(p, bf_lo(q.z), acc[4]); acc[5] = fmaf(p, bf_hi(q.z), acc[5]);
  acc[6] = fmaf(p, bf_lo(q.w), acc[6]); acc[7] = fmaf(p, bf_hi(q.w), acc[7]);
}

// --------------------- CSR build via bucketed counting sort ----------------

__global__ __launch_bounds__(256) void k_hist(
    const int* __restrict__ ei, int E, int NB, int chunk,
    int* __restrict__ gHistA, int* __restrict__ gHistB) {
  __shared__ int hA[1024], hB[1024];
  for (int i = threadIdx.x; i < NB; i += 256) { hA[i] = 0; hB[i] = 0; }
  __syncthreads();
  int e0 = blockIdx.x * chunk;
  int e1 = min(E, e0 + chunk);
  for (int e = e0 + threadIdx.x; e < e1; e += 256) {
    int s = ei[e], d = ei[E + e];
    atomicAdd(&hA[s >> BSH], 1);
    atomicAdd(&hB[d >> BSH], 1);
  }
  __syncthreads();
  for (int i = threadIdx.x; i < NB; i += 256) {
    gHistA[blockIdx.x * NB + i] = hA[i];
    gHistB[blockIdx.x * NB + i] = hB[i];
  }
}

__global__ __launch_bounds__(256) void k_colscan(
    int* __restrict__ gHist, int* __restrict__ tot, int NB) {
  __shared__ int s[GEB];
  int b = blockIdx.x;
  int t = threadIdx.x;
  int v = gHist[t * NB + b];
  s[t] = v;
  __syncthreads();
  for (int d = 1; d < GEB; d <<= 1) {
    int u = (t >= d) ? s[t - d] : 0;
    __syncthreads();
    s[t] += u;
    __syncthreads();
  }
  gHist[t * NB + b] = s[t] - v;
  if (t == GEB - 1) tot[b] = s[t];
}

__global__ __launch_bounds__(1024) void k_bscan(
    const int* __restrict__ totA, const int* __restrict__ totB,
    int* __restrict__ baseA, int* __restrict__ baseB,
    int* __restrict__ offA, int* __restrict__ offB, int NB, int N, int E) {
  __shared__ int sa[1024], sb[1024];
  int t = threadIdx.x;
  int va = (t < NB) ? totA[t] : 0;
  int vb = (t < NB) ? totB[t] : 0;
  sa[t] = va; sb[t] = vb;
  __syncthreads();
  for (int d = 1; d < 1024; d <<= 1) {
    int ua = (t >= d) ? sa[t - d] : 0;
    int ub = (t >= d) ? sb[t - d] : 0;
    __syncthreads();
    sa[t] += ua; sb[t] += ub;
    __syncthreads();
  }
  if (t < NB) { baseA[t] = sa[t] - va; baseB[t] = sb[t] - vb; }
  if (t == 0) { offA[N] = E; offB[N] = E; }
}

__global__ __launch_bounds__(256) void k_scatter(
    const int* __restrict__ ei, int E, int NB, int chunk,
    const int* __restrict__ gHistA, const int* __restrict__ gHistB,
    const int* __restrict__ baseA, const int* __restrict__ baseB,
    int2* __restrict__ pairsA, int2* __restrict__ pairsB) {
  __shared__ int cA[1024], cB[1024];
  int g = blockIdx.x;
  for (int i = threadIdx.x; i < NB; i += 256) {
    cA[i] = baseA[i] + gHistA[g * NB + i];
    cB[i] = baseB[i] + gHistB[g * NB + i];
  }
  __syncthreads();
  int e0 = g * chunk;
  int e1 = min(E, e0 + chunk);
  for (int e = e0 + threadIdx.x; e < e1; e += 256) {
    int s = ei[e], d = ei[E + e];
    int pa = atomicAdd(&cA[s >> BSH], 1);
    pairsA[pa] = {s, d};
    int pb = atomicAdd(&cB[d >> BSH], 1);
    pairsB[pb] = {s, d};
  }
}

template <int KEY>
__global__ __launch_bounds__(256) void k_bucket(
    const int2* __restrict__ pairs, const int* __restrict__ base,
    const int* __restrict__ tot, int* __restrict__ off,
    int* __restrict__ idx, float* __restrict__ dis, int N) {
  __shared__ int cnt[RNGB], pfx[RNGB];
  int b = blockIdx.x;
  int node0 = b << BSH;
  int rng = min(RNGB, N - node0);
  int bstart = base[b], bcount = tot[b];
  for (int i = threadIdx.x; i < rng; i += 256) cnt[i] = 0;
  __syncthreads();
  for (int i = threadIdx.x; i < bcount; i += 256) {
    int2 p = pairs[bstart + i];
    int loc = (KEY == 0 ? p.x : p.y) - node0;
    atomicAdd(&cnt[loc], 1);
  }
  __syncthreads();
  if (threadIdx.x == 0) {
    int run = 0;
    for (int i = 0; i < rng; ++i) { pfx[i] = run; run += cnt[i]; }
  }
  __syncthreads();
  for (int i = threadIdx.x; i < rng; i += 256) {
    off[node0 + i] = bstart + pfx[i];
    if (KEY == 1) dis[node0 + i] = rsqrtf((float)(cnt[i] + 1));
  }
  __syncthreads();
  for (int i = threadIdx.x; i < bcount; i += 256) {
    int2 p = pairs[bstart + i];
    int loc = (KEY == 0 ? p.x : p.y) - node0;
    int pos = bstart + atomicAdd(&pfx[loc], 1);
    idx[pos] = (KEY == 0 ? p.y : p.x);
  }
}

// --------------------------------- GEMMs -----------------------------------

__global__ __launch_bounds__(256) void k_gemm64(
    const float* __restrict__ X, const float* __restrict__ W,
    const float* __restrict__ dis, u32* __restrict__ Hb, int n) {
  __shared__ float Xs[64 * 65];
  int row0 = blockIdx.x * 64;
  for (int t = threadIdx.x; t < 1024; t += 256) {
    int r = t >> 4, k4 = t & 15;
    int row = row0 + r;
    float4 v = (row < n) ? ((const float4*)X)[(size_t)row * 16 + k4]
                         : float4{0.f, 0.f, 0.f, 0.f};
    float* dst = &Xs[r * 65 + k4 * 4];
    dst[0] = v.x; dst[1] = v.y; dst[2] = v.z; dst[3] = v.w;
  }
  __syncthreads();
  int lane = threadIdx.x & 63;
  int w = __builtin_amdgcn_readfirstlane(threadIdx.x >> 6);
  int c0 = w * 16;
  int row = row0 + lane;
  float acc[16];
#pragma unroll
  for (int c = 0; c < 16; ++c) acc[c] = 0.f;
#pragma unroll 4
  for (int k = 0; k < 64; ++k) {
    float xk = Xs[lane * 65 + k];
#pragma unroll
    for (int c = 0; c < 16; ++c)
      acc[c] = fmaf(xk, W[k * 64 + c0 + c], acc[c]);
  }
  if (row >= n) return;
  float sc = dis[row];
  uint4* H4 = (uint4*)Hb;
  uint4 o0 = {pack_bf16(acc[0] * sc, acc[1] * sc), pack_bf16(acc[2] * sc, acc[3] * sc),
              pack_bf16(acc[4] * sc, acc[5] * sc), pack_bf16(acc[6] * sc, acc[7] * sc)};
  uint4 o1 = {pack_bf16(acc[8] * sc, acc[9] * sc), pack_bf16(acc[10] * sc, acc[11] * sc),
              pack_bf16(acc[12] * sc, acc[13] * sc), pack_bf16(acc[14] * sc, acc[15] * sc)};
  H4[(size_t)row * 8 + w * 2] = o0;
  H4[(size_t)row * 8 + w * 2 + 1] = o1;
}

__global__ __launch_bounds__(256) void k_gat_gemm(
    const u32* __restrict__ Xb, const float* __restrict__ W,
    const float* __restrict__ asrc, const float* __restrict__ adst,
    u32* __restrict__ Hgb, float* __restrict__ al, int n) {
  __shared__ float Xs[64 * 65];
  int row0 = blockIdx.x * 64;
  for (int t = threadIdx.x; t < 512; t += 256) {
    int r = t >> 3, k8 = t & 7;
    int row = row0 + r;
    uint4 xw = (row < n) ? ((const uint4*)Xb)[(size_t)row * 8 + k8]
                         : uint4{0u, 0u, 0u, 0u};
    float* dst = &Xs[r * 65 + k8 * 8];
    dst[0] = bf_lo(xw.x); dst[1] = bf_hi(xw.x);
    dst[2] = bf_lo(xw.y); dst[3] = bf_hi(xw.y);
    dst[4] = bf_lo(xw.z); dst[5] = bf_hi(xw.z);
    dst[6] = bf_lo(xw.w); dst[7] = bf_hi(xw.w);
  }
  __syncthreads();
  int lane = threadIdx.x & 63;
  int w = __builtin_amdgcn_readfirstlane(threadIdx.x >> 6);
  int c0 = w * 16;
  int row = row0 + lane;
  float acc[16];
#pragma unroll
  for (int c = 0; c < 16; ++c) acc[c] = 0.f;
#pragma unroll 4
  for (int k = 0; k < 64; ++k) {
    float xk = Xs[lane * 65 + k];
#pragma unroll
    for (int c = 0; c < 16; ++c) {
      int gc = c0 + c;
      acc[c] = fmaf(xk, W[(gc >> 3) * 512 + k * 8 + (gc & 7)], acc[c]);
    }
  }
  if (row >= n) return;
  float s1a = 0.f, s2a = 0.f, s1b = 0.f, s2b = 0.f;
#pragma unroll
  for (int cc = 0; cc < 8; ++cc) {
    s1a = fmaf(acc[cc], asrc[c0 + cc], s1a);
    s2a = fmaf(acc[cc], adst[c0 + cc], s2a);
    s1b = fmaf(acc[8 + cc], asrc[c0 + 8 + cc], s1b);
    s2b = fmaf(acc[8 + cc], adst[c0 + 8 + cc], s2b);
  }
  float2* al2 = (float2*)al;
  al2[(size_t)row * 8 + w] = {s1a, s1b};
  al2[(size_t)row * 8 + 4 + w] = {s2a, s2b};
  uint4* H4 = (uint4*)Hgb;
  uint4 o0 = {pack_bf16(acc[0], acc[1]), pack_bf16(acc[2], acc[3]),
              pack_bf16(acc[4], acc[5]), pack_bf16(acc[6], acc[7])};
  uint4 o1 = {pack_bf16(acc[8], acc[9]), pack_bf16(acc[10], acc[11]),
              pack_bf16(acc[12], acc[13]), pack_bf16(acc[14], acc[15])};
  H4[(size_t)row * 8 + w * 2] = o0;
  H4[(size_t)row * 8 + w * 2 + 1] = o1;
}

// ------------------------------ aggregations -------------------------------

enum { MODE_RW1 = 0, MODE_RW = 1, MODE_G0 = 2, MODE_GR = 3, MODE_GD = 4 };

template <int MODE>
__global__ __launch_bounds__(256) void k_agg(
    const int* __restrict__ off, const int* __restrict__ idx,
    const float* __restrict__ Hf, const u32* __restrict__ Hb,
    const float* __restrict__ dis, const float* __restrict__ bias,
    float* __restrict__ R, float* __restrict__ Xf, u32* __restrict__ Xb,
    int n) {
  int lane = threadIdx.x & 63;
  int d = blockIdx.x * 4 + (threadIdx.x >> 6);
  if (d >= n) return;
  int rg = lane >> 3, cg = lane & 7;
  int beg = off[d], end = off[d + 1];
  const uint4* H4b = (const uint4*)Hb;
  const float4* H4f = (const float4*)Hf;
  float acc[8];
#pragma unroll
  for (int i = 0; i < 8; ++i) acc[i] = 0.f;
  for (int base = beg; base < end; base += 64) {
    int cnt = end - base;
    if (cnt > 64) cnt = 64;
    int sidx = (lane < cnt) ? idx[base + lane] : -1;
    int nIter = (cnt + 7) >> 3;
    int j = 0;
    // 2-deep pipelined gather: both loads issued before either accumulate.
    for (; j + 2 <= nIter; j += 2) {
      int s0 = __shfl(sidx, j * 8 + rg, 64);
      int s1 = __shfl(sidx, j * 8 + 8 + rg, 64);
      size_t a0 = (size_t)(s0 >= 0 ? s0 : 0);
      size_t a1 = (size_t)(s1 >= 0 ? s1 : 0);
      if (MODE == MODE_RW1) {
        float4 x0 = H4f[a0 * 16 + cg * 2], y0 = H4f[a0 * 16 + cg * 2 + 1];
        float4 x1 = H4f[a1 * 16 + cg * 2], y1 = H4f[a1 * 16 + cg * 2 + 1];
        if (s0 < 0) { x0 = {0,0,0,0}; y0 = {0,0,0,0}; }
        if (s1 < 0) { x1 = {0,0,0,0}; y1 = {0,0,0,0}; }
        acc[0] += x0.x; acc[1] += x0.y; acc[2] += x0.z; acc[3] += x0.w;
        acc[4] += y0.x; acc[5] += y0.y; acc[6] += y0.z; acc[7] += y0.w;
        acc[0] += x1.x; acc[1] += x1.y; acc[2] += x1.z; acc[3] += x1.w;
        acc[4] += y1.x; acc[5] += y1.y; acc[6] += y1.z; acc[7] += y1.w;
      } else {
        uint4 q0 = H4b[a0 * 8 + cg];
        uint4 q1 = H4b[a1 * 8 + cg];
        if (s0 < 0) q0 = {0u,0u,0u,0u};
        if (s1 < 0) q1 = {0u,0u,0u,0u};
        acc8(acc, q0);
        acc8(acc, q1);
      }
    }
    if (j < nIter) {
      int s0 = __shfl(sidx, j * 8 + rg, 64);
      size_t a0 = (size_t)(s0 >= 0 ? s0 : 0);
      if (MODE == MODE_RW1) {
        float4 x0 = H4f[a0 * 16 + cg * 2], y0 = H4f[a0 * 16 + cg * 2 + 1];
        if (s0 < 0) { x0 = {0,0,0,0}; y0 = {0,0,0,0}; }
        acc[0] += x0.x; acc[1] += x0.y; acc[2] += x0.z; acc[3] += x0.w;
        acc[4] += y0.x; acc[5] += y0.y; acc[6] += y0.z; acc[7] += y0.w;
      } else {
        uint4 q0 = H4b[a0 * 8 + cg];
        if (s0 < 0) q0 = {0u,0u,0u,0u};
        acc8(acc, q0);
      }
    }
  }
#pragma unroll
  for (int m = 8; m < 64; m <<= 1)
#pragma unroll
    for (int i = 0; i < 8; ++i) acc[i] += __shfl_xor(acc[i], m, 64);
  if (rg != 0) return;
  if (MODE == MODE_RW1 || MODE == MODE_RW) {
    uint4 o = {pack_bf16(acc[0], acc[1]), pack_bf16(acc[2], acc[3]),
               pack_bf16(acc[4], acc[5]), pack_bf16(acc[6], acc[7])};
    ((uint4*)Xb)[(size_t)d * 8 + cg] = o;
    return;
  }
  float ddv = dis[d];
  uint4 hw = H4b[(size_t)d * 8 + cg];
  float hs[8] = {bf_lo(hw.x), bf_hi(hw.x), bf_lo(hw.y), bf_hi(hw.y),
                 bf_lo(hw.z), bf_hi(hw.z), bf_lo(hw.w), bf_hi(hw.w)};
  float4 b0 = ((const float4*)bias)[cg * 2];
  float4 b1 = ((const float4*)bias)[cg * 2 + 1];
  float bv[8] = {b0.x, b0.y, b0.z, b0.w, b1.x, b1.y, b1.z, b1.w};
  float v[8];
#pragma unroll
  for (int i = 0; i < 8; ++i) v[i] = ddv * (acc[i] + hs[i]) + bv[i];
  float4* X4 = (float4*)Xf;
  size_t o0 = (size_t)d * 16 + cg * 2;
  if (MODE == MODE_GR) {
    float4* R4 = (float4*)R;
    float4 r0 = R4[o0], r1 = R4[o0 + 1];
    v[0] += r0.x; v[1] += r0.y; v[2] += r0.z; v[3] += r0.w;
    v[4] += r1.x; v[5] += r1.y; v[6] += r1.z; v[7] += r1.w;
    R4[o0] = {v[0], v[1], v[2], v[3]};
    R4[o0 + 1] = {v[4], v[5], v[6], v[7]};
    X4[o0] = {fmaxf(v[0], 0.f), fmaxf(v[1], 0.f), fmaxf(v[2], 0.f), fmaxf(v[3], 0.f)};
    X4[o0 + 1] = {fmaxf(v[4], 0.f), fmaxf(v[5], 0.f), fmaxf(v[6], 0.f), fmaxf(v[7], 0.f)};
  } else if (MODE == MODE_GD) {
    float4 x0 = X4[o0], x1 = X4[o0 + 1];
    X4[o0] = {x0.x + v[0], x0.y + v[1], x0.z + v[2], x0.w + v[3]};
    X4[o0 + 1] = {x1.x + v[4], x1.y + v[5], x1.z + v[6], x1.w + v[7]};
  } else {  // MODE_G0
    X4[o0] = {fmaxf(v[0], 0.f), fmaxf(v[1], 0.f), fmaxf(v[2], 0.f), fmaxf(v[3], 0.f)};
    X4[o0 + 1] = {fmaxf(v[4], 0.f), fmaxf(v[5], 0.f), fmaxf(v[6], 0.f), fmaxf(v[7], 0.f)};
  }
}

__global__ __launch_bounds__(256) void k_gat_agg(
    const int* __restrict__ off, const int* __restrict__ idx,
    const u32* __restrict__ Hgb, const float* __restrict__ al,
    const float* __restrict__ bias, float* __restrict__ X,
    float* __restrict__ R, int n) {
  int lane = threadIdx.x & 63;
  int d = blockIdx.x * 4 + (threadIdx.x >> 6);
  if (d >= n) return;
  int rg = lane >> 3, cg = lane & 7;
  const uint4* H4b = (const uint4*)Hgb;
  float ald = al[(size_t)d * 16 + 8 + cg];
  float eself = lrelu(al[(size_t)d * 16 + cg] + ald);
  int beg = off[d], end = off[d + 1];
  // pass 1: per-head max (2-deep pipelined)
  float m = eself;
  for (int base = beg; base < end; base += 64) {
    int cnt = end - base;
    if (cnt > 64) cnt = 64;
    int sidx = (lane < cnt) ? idx[base + lane] : -1;
    int nIter = (cnt + 7) >> 3;
    int j = 0;
    for (; j + 2 <= nIter; j += 2) {
      int s0 = __shfl(sidx, j * 8 + rg, 64);
      int s1 = __shfl(sidx, j * 8 + 8 + rg, 64);
      float a0 = al[(size_t)(s0 >= 0 ? s0 : 0) * 16 + cg];
      float a1 = al[(size_t)(s1 >= 0 ? s1 : 0) * 16 + cg];
      if (s0 >= 0) m = fmaxf(m, lrelu(a0 + ald));
      if (s1 >= 0) m = fmaxf(m, lrelu(a1 + ald));
    }
    if (j < nIter) {
      int s0 = __shfl(sidx, j * 8 + rg, 64);
      float a0 = al[(size_t)(s0 >= 0 ? s0 : 0) * 16 + cg];
      if (s0 >= 0) m = fmaxf(m, lrelu(a0 + ald));
    }
  }
#pragma unroll
  for (int mm = 8; mm < 64; mm <<= 1) m = fmaxf(m, __shfl_xor(m, mm, 64));
  // pass 2: weighted sum (2-deep pipelined: 2x al + 2x Hgb in flight)
  float denom = 0.f;
  float acc[8];
#pragma unroll
  for (int i = 0; i < 8; ++i) acc[i] = 0.f;
  for (int base = beg; base < end; base += 64) {
    int cnt = end - base;
    if (cnt > 64) cnt = 64;
    int sidx = (lane < cnt) ? idx[base + lane] : -1;
    int nIter = (cnt + 7) >> 3;
    int j = 0;
    for (; j + 2 <= nIter; j += 2) {
      int s0 = __shfl(sidx, j * 8 + rg, 64);
      int s1 = __shfl(sidx, j * 8 + 8 + rg, 64);
      size_t a0 = (size_t)(s0 >= 0 ? s0 : 0);
      size_t a1 = (size_t)(s1 >= 0 ? s1 : 0);
      float l0 = al[a0 * 16 + cg];
      float l1 = al[a1 * 16 + cg];
      uint4 q0 = H4b[a0 * 8 + cg];
      uint4 q1 = H4b[a1 * 8 + cg];
      float p0 = (s0 >= 0) ? __expf(lrelu(l0 + ald) - m) : 0.f;
      float p1 = (s1 >= 0) ? __expf(lrelu(l1 + ald) - m) : 0.f;
      denom += p0;
      fma8(acc, p0, q0);
      denom += p1;
      fma8(acc, p1, q1);
    }
    if (j < nIter) {
      int s0 = __shfl(sidx, j * 8 + rg, 64);
      size_t a0 = (size_t)(s0 >= 0 ? s0 : 0);
      float l0 = al[a0 * 16 + cg];
      uint4 q0 = H4b[a0 * 8 + cg];
      float p0 = (s0 >= 0) ? __expf(lrelu(l0 + ald) - m) : 0.f;
      denom += p0;
      fma8(acc, p0, q0);
    }
  }
#pragma unroll
  for (int mm = 8; mm < 64; mm <<= 1) {
#pragma unroll
    for (int i = 0; i < 8; ++i) acc[i] += __shfl_xor(acc[i], mm, 64);
    denom += __shfl_xor(denom, mm, 64);
  }
  if (rg != 0) return;
  float pself = __expf(eself - m);
  uint4 hw = H4b[(size_t)d * 8 + cg];
  float hs[8] = {bf_lo(hw.x), bf_hi(hw.x), bf_lo(hw.y), bf_hi(hw.y),
                 bf_lo(hw.z), bf_hi(hw.z), bf_lo(hw.w), bf_hi(hw.w)};
#pragma unroll
  for (int i = 0; i < 8; ++i) acc[i] = fmaf(pself, hs[i], acc[i]);
  denom += pself;
  float inv = 1.f / denom;
  float4 b0 = ((const float4*)bias)[cg * 2];
  float4 b1 = ((const float4*)bias)[cg * 2 + 1];
  float bv[8] = {b0.x, b0.y, b0.z, b0.w, b1.x, b1.y, b1.z, b1.w};
  float v[8];
#pragma unroll
  for (int i = 0; i < 8; ++i) v[i] = acc[i] * inv + bv[i];
  size_t o0 = (size_t)d * 16 + cg * 2;
  ((float4*)X)[o0] = {v[0], v[1], v[2], v[3]};
  ((float4*)X)[o0 + 1] = {v[4], v[5], v[6], v[7]};
  ((float4*)R)[o0] = {v[0], v[1], v[2], v[3]};
  ((float4*)R)[o0 + 1] = {v[4], v[5], v[6], v[7]};
}

// ------------------------------- final linear ------------------------------

__global__ __launch_bounds__(256) void k_fc(
    const float* __restrict__ X, const float* __restrict__ W,
    const float* __restrict__ b, float* __restrict__ out, int n) {
  __shared__ float Wl[640];
  __shared__ float bl[10];
  for (int i = threadIdx.x; i < 640; i += 256) Wl[i] = W[i];
  if (threadIdx.x < 10) bl[threadIdx.x] = b[threadIdx.x];
  __syncthreads();
  int r = blockIdx.x * blockDim.x + threadIdx.x;
  if (r >= n) return;
  float acc[10];
#pragma unroll
  for (int c = 0; c < 10; ++c) acc[c] = bl[c];
#pragma unroll
  for (int k = 0; k < 64; ++k) {
    float xv = X[(size_t)r * 64 + k];
#pragma unroll
    for (int c = 0; c < 10; ++c) acc[c] = fmaf(xv, Wl[k * 10 + c], acc[c]);
  }
#pragma unroll
  for (int c = 0; c < 10; ++c) out[(size_t)r * 10 + c] = acc[c];
}

// --------------------------------- launch ----------------------------------

extern "C" void kernel_launch(void* const* d_in, const int* in_sizes, int n_in,
                              void* d_out, int out_size, void* d_ws, size_t ws_size,
                              hipStream_t stream) {
  const float* x_in  = (const float*)d_in[0];
  const int*   ei    = (const int*)d_in[1];
  const float* gatW  = (const float*)d_in[2];
  const float* gatAs = (const float*)d_in[3];
  const float* gatAd = (const float*)d_in[4];
  const float* gatB  = (const float*)d_in[5];
  const float* gcnW  = (const float*)d_in[6];
  const float* gcnB  = (const float*)d_in[7];
  const float* fcW   = (const float*)d_in[8];
  const float* fcB   = (const float*)d_in[9];
  float* out = (float*)d_out;

  const int N = in_sizes[0] / 64;
  const int E = in_sizes[1] / 2;
  const int NB = (N + RNGB - 1) >> BSH;
  const int chunk = (E + GEB - 1) / GEB;

  char* ws = (char*)d_ws;
  size_t o = 0;
  auto alloc = [&](size_t bytes) -> char* {
    char* p = ws + o;
    o = (o + bytes + 255) & ~(size_t)255;
    return p;
  };
  int* offA    = (int*)alloc((size_t)(N + 1) * 4);
  int* offB    = (int*)alloc((size_t)(N + 1) * 4);
  float* dis   = (float*)alloc((size_t)N * 4);
  int* idxA    = (int*)alloc((size_t)E * 4);
  int* idxB    = (int*)alloc((size_t)E * 4);
  int2* pairsA = (int2*)alloc((size_t)E * 8);
  int2* pairsB = (int2*)alloc((size_t)E * 8);
  int* gHistA  = (int*)alloc((size_t)GEB * NB * 4);
  int* gHistB  = (int*)alloc((size_t)GEB * NB * 4);
  int* totA    = (int*)alloc((size_t)NB * 4);
  int* totB    = (int*)alloc((size_t)NB * 4);
  int* baseA   = (int*)alloc((size_t)NB * 4);
  int* baseB   = (int*)alloc((size_t)NB * 4);
  float* al    = (float*)alloc((size_t)N * 16 * 4);
  u32* B0      = (u32*)alloc((size_t)N * 32 * 4);
  u32* B1      = (u32*)alloc((size_t)N * 32 * 4);
  float* X     = (float*)alloc((size_t)N * 64 * 4);
  float* R     = (float*)alloc((size_t)N * 64 * 4);

  int nbN = (N + 255) / 256;
  int nbAgg = (N + 3) / 4;
  int nbG = (N + 63) / 64;

  // ---- CSR build: bucketed counting sort ----
  k_hist<<<GEB, 256, 0, stream>>>(ei, E, NB, chunk, gHistA, gHistB);
  k_colscan<<<NB, GEB, 0, stream>>>(gHistA, totA, NB);
  k_colscan<<<NB, GEB, 0, stream>>>(gHistB, totB, NB);
  k_bscan<<<1, 1024, 0, stream>>>(totA, totB, baseA, baseB, offA, offB, NB, N, E);
  k_scatter<<<GEB, 256, 0, stream>>>(ei, E, NB, chunk, gHistA, gHistB,
                                     baseA, baseB, pairsA, pairsB);
  k_bucket<0><<<NB, 256, 0, stream>>>(pairsA, baseA, totA, offA, idxA, nullptr, N);
  k_bucket<1><<<NB, 256, 0, stream>>>(pairsB, baseB, totB, offB, idxB, dis, N);

  // ---- random walk: 5 steps (fp32 in -> bf16 ping-pong) ----
  k_agg<MODE_RW1><<<nbAgg, 256, 0, stream>>>(offA, idxA, x_in, nullptr, nullptr, nullptr, nullptr, nullptr, B0, N);
  k_agg<MODE_RW><<<nbAgg, 256, 0, stream>>>(offA, idxA, nullptr, B0, nullptr, nullptr, nullptr, nullptr, B1, N);
  k_agg<MODE_RW><<<nbAgg, 256, 0, stream>>>(offA, idxA, nullptr, B1, nullptr, nullptr, nullptr, nullptr, B0, N);
  k_agg<MODE_RW><<<nbAgg, 256, 0, stream>>>(offA, idxA, nullptr, B0, nullptr, nullptr, nullptr, nullptr, B1, N);
  k_agg<MODE_RW><<<nbAgg, 256, 0, stream>>>(offA, idxA, nullptr, B1, nullptr, nullptr, nullptr, nullptr, B0, N);

  // ---- GAT ----
  k_gat_gemm<<<nbG, 256, 0, stream>>>(B0, gatW, gatAs, gatAd, B1, al, N);
  k_gat_agg<<<nbAgg, 256, 0, stream>>>(offB, idxB, B1, al, gatB, X, R, N);

  // ---- residual GCN ----
  for (int i = 0; i < 12; ++i) {
    k_gemm64<<<nbG, 256, 0, stream>>>(X, gcnW + i * 4096, dis, B0, N);
    if (i == 0)
      k_agg<MODE_G0><<<nbAgg, 256, 0, stream>>>(offB, idxB, nullptr, B0, dis, gcnB + i * 64, nullptr, X, nullptr, N);
    else
      k_agg<MODE_GR><<<nbAgg, 256, 0, stream>>>(offB, idxB, nullptr, B0, dis, gcnB + i * 64, R, X, nullptr, N);
    if (i < 11) {
      int j = (i == 0) ? 11 : i - 1;
      k_gemm64<<<nbG, 256, 0, stream>>>(X, gcnW + j * 4096, dis, B0, N);
      k_agg<MODE_GD><<<nbAgg, 256, 0, stream>>>(offB, idxB, nullptr, B0, dis, gcnB + j * 64, nullptr, X, nullptr, N);
    }
  }

  // ---- final linear ----
  k_fc<<<nbN, 256, 0, stream>>>(X, fcW, fcB, out, N);
}

// Round 9
// 1775.784 us; speedup vs baseline: 1.7355x; 1.0378x over previous
//
#include <hip/hip_runtime.h>

// ---------------------------------------------------------------------------
// LRA_GNN: random-walk -> 8-head GAT -> 12-layer residual GCN -> FC.
// Round 9: TWO destination nodes per wave in all aggregation kernels — the
// per-node dependency chain (off->idx->shfl->gather->reduce) was the latency
// limit (deg~16 => only 2 row-group loads per node). Two interleaved chains
// per wave double in-flight work. Per-node math order unchanged (absmax must
// stay 1664). CSR counting-sort build, LDS-staged GEMMs unchanged.
// ---------------------------------------------------------------------------

typedef unsigned int u32;

#define BSH 7              // bucket shift: 128 nodes per bucket
#define RNGB 128           // nodes per bucket
#define GEB 256            // edge-pass blocks

__device__ __forceinline__ float lrelu(float v) { return v > 0.f ? v : 0.2f * v; }
__device__ __forceinline__ float bf_lo(u32 w) { return __uint_as_float(w << 16); }
__device__ __forceinline__ float bf_hi(u32 w) { return __uint_as_float(w & 0xffff0000u); }
__device__ __forceinline__ u32 pack_bf16(float a, float b) {
  u32 ua = __float_as_uint(a); ua = ua + 0x7fffu + ((ua >> 16) & 1u);
  u32 ub = __float_as_uint(b); ub = ub + 0x7fffu + ((ub >> 16) & 1u);
  return (ua >> 16) | (ub & 0xffff0000u);
}
__device__ __forceinline__ void acc8(float* acc, uint4 q) {
  acc[0] += bf_lo(q.x); acc[1] += bf_hi(q.x);
  acc[2] += bf_lo(q.y); acc[3] += bf_hi(q.y);
  acc[4] += bf_lo(q.z); acc[5] += bf_hi(q.z);
  acc[6] += bf_lo(q.w); acc[7] += bf_hi(q.w);
}
__device__ __forceinline__ void fma8(float* acc, float p, uint4 q) {
  acc[0] = fmaf(p, bf_lo(q.x), acc[0]); acc[1] = fmaf(p, bf_hi(q.x), acc[1]);
  acc[2] = fmaf(p, bf_lo(q.y), acc[2]); acc[3] = fmaf(p, bf_hi(q.y), acc[3]);
  acc[4] = fmaf(p, bf_lo(q.z), acc[4]); acc[5] = fmaf(p, bf_hi(q.z), acc[5]);
  acc[6] = fmaf(p, bf_lo(q.w), acc[6]); acc[7] = fmaf(p, bf_hi(q.w), acc[7]);
}

// --------------------- CSR build via bucketed counting sort ----------------

__global__ __launch_bounds__(256) void k_hist(
    const int* __restrict__ ei, int E, int NB, int chunk,
    int* __restrict__ gHistA, int* __restrict__ gHistB) {
  __shared__ int hA[1024], hB[1024];
  for (int i = threadIdx.x; i < NB; i += 256) { hA[i] = 0; hB[i] = 0; }
  __syncthreads();
  int e0 = blockIdx.x * chunk;
  int e1 = min(E, e0 + chunk);
  for (int e = e0 + threadIdx.x; e < e1; e += 256) {
    int s = ei[e], d = ei[E + e];
    atomicAdd(&hA[s >> BSH], 1);
    atomicAdd(&hB[d >> BSH], 1);
  }
  __syncthreads();
  for (int i = threadIdx.x; i < NB; i += 256) {
    gHistA[blockIdx.x * NB + i] = hA[i];
    gHistB[blockIdx.x * NB + i] = hB[i];
  }
}

__global__ __launch_bounds__(256) void k_colscan(
    int* __restrict__ gHist, int* __restrict__ tot, int NB) {
  __shared__ int s[GEB];
  int b = blockIdx.x;
  int t = threadIdx.x;
  int v = gHist[t * NB + b];
  s[t] = v;
  __syncthreads();
  for (int d = 1; d < GEB; d <<= 1) {
    int u = (t >= d) ? s[t - d] : 0;
    __syncthreads();
    s[t] += u;
    __syncthreads();
  }
  gHist[t * NB + b] = s[t] - v;
  if (t == GEB - 1) tot[b] = s[t];
}

__global__ __launch_bounds__(1024) void k_bscan(
    const int* __restrict__ totA, const int* __restrict__ totB,
    int* __restrict__ baseA, int* __restrict__ baseB,
    int* __restrict__ offA, int* __restrict__ offB, int NB, int N, int E) {
  __shared__ int sa[1024], sb[1024];
  int t = threadIdx.x;
  int va = (t < NB) ? totA[t] : 0;
  int vb = (t < NB) ? totB[t] : 0;
  sa[t] = va; sb[t] = vb;
  __syncthreads();
  for (int d = 1; d < 1024; d <<= 1) {
    int ua = (t >= d) ? sa[t - d] : 0;
    int ub = (t >= d) ? sb[t - d] : 0;
    __syncthreads();
    sa[t] += ua; sb[t] += ub;
    __syncthreads();
  }
  if (t < NB) { baseA[t] = sa[t] - va; baseB[t] = sb[t] - vb; }
  if (t == 0) { offA[N] = E; offB[N] = E; }
}

__global__ __launch_bounds__(256) void k_scatter(
    const int* __restrict__ ei, int E, int NB, int chunk,
    const int* __restrict__ gHistA, const int* __restrict__ gHistB,
    const int* __restrict__ baseA, const int* __restrict__ baseB,
    int2* __restrict__ pairsA, int2* __restrict__ pairsB) {
  __shared__ int cA[1024], cB[1024];
  int g = blockIdx.x;
  for (int i = threadIdx.x; i < NB; i += 256) {
    cA[i] = baseA[i] + gHistA[g * NB + i];
    cB[i] = baseB[i] + gHistB[g * NB + i];
  }
  __syncthreads();
  int e0 = g * chunk;
  int e1 = min(E, e0 + chunk);
  for (int e = e0 + threadIdx.x; e < e1; e += 256) {
    int s = ei[e], d = ei[E + e];
    int pa = atomicAdd(&cA[s >> BSH], 1);
    pairsA[pa] = {s, d};
    int pb = atomicAdd(&cB[d >> BSH], 1);
    pairsB[pb] = {s, d};
  }
}

template <int KEY>
__global__ __launch_bounds__(256) void k_bucket(
    const int2* __restrict__ pairs, const int* __restrict__ base,
    const int* __restrict__ tot, int* __restrict__ off,
    int* __restrict__ idx, float* __restrict__ dis, int N) {
  __shared__ int cnt[RNGB], pfx[RNGB];
  int b = blockIdx.x;
  int node0 = b << BSH;
  int rng = min(RNGB, N - node0);
  int bstart = base[b], bcount = tot[b];
  for (int i = threadIdx.x; i < rng; i += 256) cnt[i] = 0;
  __syncthreads();
  for (int i = threadIdx.x; i < bcount; i += 256) {
    int2 p = pairs[bstart + i];
    int loc = (KEY == 0 ? p.x : p.y) - node0;
    atomicAdd(&cnt[loc], 1);
  }
  __syncthreads();
  if (threadIdx.x == 0) {
    int run = 0;
    for (int i = 0; i < rng; ++i) { pfx[i] = run; run += cnt[i]; }
  }
  __syncthreads();
  for (int i = threadIdx.x; i < rng; i += 256) {
    off[node0 + i] = bstart + pfx[i];
    if (KEY == 1) dis[node0 + i] = rsqrtf((float)(cnt[i] + 1));
  }
  __syncthreads();
  for (int i = threadIdx.x; i < bcount; i += 256) {
    int2 p = pairs[bstart + i];
    int loc = (KEY == 0 ? p.x : p.y) - node0;
    int pos = bstart + atomicAdd(&pfx[loc], 1);
    idx[pos] = (KEY == 0 ? p.y : p.x);
  }
}

// --------------------------------- GEMMs -----------------------------------

__global__ __launch_bounds__(256) void k_gemm64(
    const float* __restrict__ X, const float* __restrict__ W,
    const float* __restrict__ dis, u32* __restrict__ Hb, int n) {
  __shared__ float Xs[64 * 65];
  int row0 = blockIdx.x * 64;
  for (int t = threadIdx.x; t < 1024; t += 256) {
    int r = t >> 4, k4 = t & 15;
    int row = row0 + r;
    float4 v = (row < n) ? ((const float4*)X)[(size_t)row * 16 + k4]
                         : float4{0.f, 0.f, 0.f, 0.f};
    float* dst = &Xs[r * 65 + k4 * 4];
    dst[0] = v.x; dst[1] = v.y; dst[2] = v.z; dst[3] = v.w;
  }
  __syncthreads();
  int lane = threadIdx.x & 63;
  int w = __builtin_amdgcn_readfirstlane(threadIdx.x >> 6);
  int c0 = w * 16;
  int row = row0 + lane;
  float acc[16];
#pragma unroll
  for (int c = 0; c < 16; ++c) acc[c] = 0.f;
#pragma unroll 4
  for (int k = 0; k < 64; ++k) {
    float xk = Xs[lane * 65 + k];
#pragma unroll
    for (int c = 0; c < 16; ++c)
      acc[c] = fmaf(xk, W[k * 64 + c0 + c], acc[c]);
  }
  if (row >= n) return;
  float sc = dis[row];
  uint4* H4 = (uint4*)Hb;
  uint4 o0 = {pack_bf16(acc[0] * sc, acc[1] * sc), pack_bf16(acc[2] * sc, acc[3] * sc),
              pack_bf16(acc[4] * sc, acc[5] * sc), pack_bf16(acc[6] * sc, acc[7] * sc)};
  uint4 o1 = {pack_bf16(acc[8] * sc, acc[9] * sc), pack_bf16(acc[10] * sc, acc[11] * sc),
              pack_bf16(acc[12] * sc, acc[13] * sc), pack_bf16(acc[14] * sc, acc[15] * sc)};
  H4[(size_t)row * 8 + w * 2] = o0;
  H4[(size_t)row * 8 + w * 2 + 1] = o1;
}

__global__ __launch_bounds__(256) void k_gat_gemm(
    const u32* __restrict__ Xb, const float* __restrict__ W,
    const float* __restrict__ asrc, const float* __restrict__ adst,
    u32* __restrict__ Hgb, float* __restrict__ al, int n) {
  __shared__ float Xs[64 * 65];
  int row0 = blockIdx.x * 64;
  for (int t = threadIdx.x; t < 512; t += 256) {
    int r = t >> 3, k8 = t & 7;
    int row = row0 + r;
    uint4 xw = (row < n) ? ((const uint4*)Xb)[(size_t)row * 8 + k8]
                         : uint4{0u, 0u, 0u, 0u};
    float* dst = &Xs[r * 65 + k8 * 8];
    dst[0] = bf_lo(xw.x); dst[1] = bf_hi(xw.x);
    dst[2] = bf_lo(xw.y); dst[3] = bf_hi(xw.y);
    dst[4] = bf_lo(xw.z); dst[5] = bf_hi(xw.z);
    dst[6] = bf_lo(xw.w); dst[7] = bf_hi(xw.w);
  }
  __syncthreads();
  int lane = threadIdx.x & 63;
  int w = __builtin_amdgcn_readfirstlane(threadIdx.x >> 6);
  int c0 = w * 16;
  int row = row0 + lane;
  float acc[16];
#pragma unroll
  for (int c = 0; c < 16; ++c) acc[c] = 0.f;
#pragma unroll 4
  for (int k = 0; k < 64; ++k) {
    float xk = Xs[lane * 65 + k];
#pragma unroll
    for (int c = 0; c < 16; ++c) {
      int gc = c0 + c;
      acc[c] = fmaf(xk, W[(gc >> 3) * 512 + k * 8 + (gc & 7)], acc[c]);
    }
  }
  if (row >= n) return;
  float s1a = 0.f, s2a = 0.f, s1b = 0.f, s2b = 0.f;
#pragma unroll
  for (int cc = 0; cc < 8; ++cc) {
    s1a = fmaf(acc[cc], asrc[c0 + cc], s1a);
    s2a = fmaf(acc[cc], adst[c0 + cc], s2a);
    s1b = fmaf(acc[8 + cc], asrc[c0 + 8 + cc], s1b);
    s2b = fmaf(acc[8 + cc], adst[c0 + 8 + cc], s2b);
  }
  float2* al2 = (float2*)al;
  al2[(size_t)row * 8 + w] = {s1a, s1b};
  al2[(size_t)row * 8 + 4 + w] = {s2a, s2b};
  uint4* H4 = (uint4*)Hgb;
  uint4 o0 = {pack_bf16(acc[0], acc[1]), pack_bf16(acc[2], acc[3]),
              pack_bf16(acc[4], acc[5]), pack_bf16(acc[6], acc[7])};
  uint4 o1 = {pack_bf16(acc[8], acc[9]), pack_bf16(acc[10], acc[11]),
              pack_bf16(acc[12], acc[13]), pack_bf16(acc[14], acc[15])};
  H4[(size_t)row * 8 + w * 2] = o0;
  H4[(size_t)row * 8 + w * 2 + 1] = o1;
}

// ------------------------------ aggregations -------------------------------

enum { MODE_RW1 = 0, MODE_RW = 1, MODE_G0 = 2, MODE_GR = 3, MODE_GD = 4 };

// Two destination nodes per wave (d0=even, d1=odd). lane = (rg 0..7, cg 0..7).
// Up to 4 gather loads in flight: 2 row-groups x 2 nodes.
template <int MODE>
__global__ __launch_bounds__(256) void k_agg(
    const int* __restrict__ off, const int* __restrict__ idx,
    const float* __restrict__ Hf, const u32* __restrict__ Hb,
    const float* __restrict__ dis, const float* __restrict__ bias,
    float* __restrict__ R, float* __restrict__ Xf, u32* __restrict__ Xb,
    int n) {
  int lane = threadIdx.x & 63;
  int wid = threadIdx.x >> 6;
  int d0 = blockIdx.x * 8 + wid * 2;
  if (d0 >= n) return;
  int d1 = d0 + 1;
  bool has1 = d1 < n;
  int rg = lane >> 3, cg = lane & 7;
  const uint4* H4b = (const uint4*)Hb;
  const float4* H4f = (const float4*)Hf;
  int beg0 = off[d0], end0 = off[d0 + 1];
  int beg1 = has1 ? off[d1] : 0, end1 = has1 ? off[d1 + 1] : 0;
  int cnt0 = end0 - beg0, cnt1 = end1 - beg1;
  int cmax = cnt0 > cnt1 ? cnt0 : cnt1;
  float acc0[8], acc1[8];
#pragma unroll
  for (int i = 0; i < 8; ++i) { acc0[i] = 0.f; acc1[i] = 0.f; }
  for (int base = 0; base < cmax; base += 64) {
    int c0 = cnt0 - base; if (c0 > 64) c0 = 64;
    int c1 = cnt1 - base; if (c1 > 64) c1 = 64;
    int sidx0 = (lane < c0) ? idx[beg0 + base + lane] : -1;
    int sidx1 = (lane < c1) ? idx[beg1 + base + lane] : -1;
    int hi = c0 > c1 ? c0 : c1;
    int nI = (hi + 7) >> 3;
    int j = 0;
    for (; j + 2 <= nI; j += 2) {
      int s00 = __shfl(sidx0, j * 8 + rg, 64);
      int s01 = __shfl(sidx0, j * 8 + 8 + rg, 64);
      int s10 = __shfl(sidx1, j * 8 + rg, 64);
      int s11 = __shfl(sidx1, j * 8 + 8 + rg, 64);
      size_t a00 = (size_t)(s00 >= 0 ? s00 : 0);
      size_t a01 = (size_t)(s01 >= 0 ? s01 : 0);
      size_t a10 = (size_t)(s10 >= 0 ? s10 : 0);
      size_t a11 = (size_t)(s11 >= 0 ? s11 : 0);
      if (MODE == MODE_RW1) {
        float4 x00 = H4f[a00 * 16 + cg * 2], y00 = H4f[a00 * 16 + cg * 2 + 1];
        float4 x01 = H4f[a01 * 16 + cg * 2], y01 = H4f[a01 * 16 + cg * 2 + 1];
        float4 x10 = H4f[a10 * 16 + cg * 2], y10 = H4f[a10 * 16 + cg * 2 + 1];
        float4 x11 = H4f[a11 * 16 + cg * 2], y11 = H4f[a11 * 16 + cg * 2 + 1];
        if (s00 < 0) { x00 = {0,0,0,0}; y00 = {0,0,0,0}; }
        if (s01 < 0) { x01 = {0,0,0,0}; y01 = {0,0,0,0}; }
        if (s10 < 0) { x10 = {0,0,0,0}; y10 = {0,0,0,0}; }
        if (s11 < 0) { x11 = {0,0,0,0}; y11 = {0,0,0,0}; }
        acc0[0] += x00.x; acc0[1] += x00.y; acc0[2] += x00.z; acc0[3] += x00.w;
        acc0[4] += y00.x; acc0[5] += y00.y; acc0[6] += y00.z; acc0[7] += y00.w;
        acc0[0] += x01.x; acc0[1] += x01.y; acc0[2] += x01.z; acc0[3] += x01.w;
        acc0[4] += y01.x; acc0[5] += y01.y; acc0[6] += y01.z; acc0[7] += y01.w;
        acc1[0] += x10.x; acc1[1] += x10.y; acc1[2] += x10.z; acc1[3] += x10.w;
        acc1[4] += y10.x; acc1[5] += y10.y; acc1[6] += y10.z; acc1[7] += y10.w;
        acc1[0] += x11.x; acc1[1] += x11.y; acc1[2] += x11.z; acc1[3] += x11.w;
        acc1[4] += y11.x; acc1[5] += y11.y; acc1[6] += y11.z; acc1[7] += y11.w;
      } else {
        uint4 q00 = H4b[a00 * 8 + cg];
        uint4 q01 = H4b[a01 * 8 + cg];
        uint4 q10 = H4b[a10 * 8 + cg];
        uint4 q11 = H4b[a11 * 8 + cg];
        if (s00 < 0) q00 = {0u,0u,0u,0u};
        if (s01 < 0) q01 = {0u,0u,0u,0u};
        if (s10 < 0) q10 = {0u,0u,0u,0u};
        if (s11 < 0) q11 = {0u,0u,0u,0u};
        acc8(acc0, q00);
        acc8(acc0, q01);
        acc8(acc1, q10);
        acc8(acc1, q11);
      }
    }
    if (j < nI) {
      int s00 = __shfl(sidx0, j * 8 + rg, 64);
      int s10 = __shfl(sidx1, j * 8 + rg, 64);
      size_t a00 = (size_t)(s00 >= 0 ? s00 : 0);
      size_t a10 = (size_t)(s10 >= 0 ? s10 : 0);
      if (MODE == MODE_RW1) {
        float4 x00 = H4f[a00 * 16 + cg * 2], y00 = H4f[a00 * 16 + cg * 2 + 1];
        float4 x10 = H4f[a10 * 16 + cg * 2], y10 = H4f[a10 * 16 + cg * 2 + 1];
        if (s00 < 0) { x00 = {0,0,0,0}; y00 = {0,0,0,0}; }
        if (s10 < 0) { x10 = {0,0,0,0}; y10 = {0,0,0,0}; }
        acc0[0] += x00.x; acc0[1] += x00.y; acc0[2] += x00.z; acc0[3] += x00.w;
        acc0[4] += y00.x; acc0[5] += y00.y; acc0[6] += y00.z; acc0[7] += y00.w;
        acc1[0] += x10.x; acc1[1] += x10.y; acc1[2] += x10.z; acc1[3] += x10.w;
        acc1[4] += y10.x; acc1[5] += y10.y; acc1[6] += y10.z; acc1[7] += y10.w;
      } else {
        uint4 q00 = H4b[a00 * 8 + cg];
        uint4 q10 = H4b[a10 * 8 + cg];
        if (s00 < 0) q00 = {0u,0u,0u,0u};
        if (s10 < 0) q10 = {0u,0u,0u,0u};
        acc8(acc0, q00);
        acc8(acc1, q10);
      }
    }
  }
#pragma unroll
  for (int m = 8; m < 64; m <<= 1)
#pragma unroll
    for (int i = 0; i < 8; ++i) {
      acc0[i] += __shfl_xor(acc0[i], m, 64);
      acc1[i] += __shfl_xor(acc1[i], m, 64);
    }
  if (rg != 0) return;
  // lanes 0..7, cg == lane; handle node d0 then d1.
#pragma unroll
  for (int nd = 0; nd < 2; ++nd) {
    int d = nd == 0 ? d0 : d1;
    if (nd == 1 && !has1) break;
    float* acc = nd == 0 ? acc0 : acc1;
    if (MODE == MODE_RW1 || MODE == MODE_RW) {
      uint4 o = {pack_bf16(acc[0], acc[1]), pack_bf16(acc[2], acc[3]),
                 pack_bf16(acc[4], acc[5]), pack_bf16(acc[6], acc[7])};
      ((uint4*)Xb)[(size_t)d * 8 + cg] = o;
      continue;
    }
    float ddv = dis[d];
    uint4 hw = H4b[(size_t)d * 8 + cg];
    float hs[8] = {bf_lo(hw.x), bf_hi(hw.x), bf_lo(hw.y), bf_hi(hw.y),
                   bf_lo(hw.z), bf_hi(hw.z), bf_lo(hw.w), bf_hi(hw.w)};
    float4 b0 = ((const float4*)bias)[cg * 2];
    float4 b1 = ((const float4*)bias)[cg * 2 + 1];
    float bv[8] = {b0.x, b0.y, b0.z, b0.w, b1.x, b1.y, b1.z, b1.w};
    float v[8];
#pragma unroll
    for (int i = 0; i < 8; ++i) v[i] = ddv * (acc[i] + hs[i]) + bv[i];
    float4* X4 = (float4*)Xf;
    size_t o0 = (size_t)d * 16 + cg * 2;
    if (MODE == MODE_GR) {
      float4* R4 = (float4*)R;
      float4 r0 = R4[o0], r1 = R4[o0 + 1];
      v[0] += r0.x; v[1] += r0.y; v[2] += r0.z; v[3] += r0.w;
      v[4] += r1.x; v[5] += r1.y; v[6] += r1.z; v[7] += r1.w;
      R4[o0] = {v[0], v[1], v[2], v[3]};
      R4[o0 + 1] = {v[4], v[5], v[6], v[7]};
      X4[o0] = {fmaxf(v[0], 0.f), fmaxf(v[1], 0.f), fmaxf(v[2], 0.f), fmaxf(v[3], 0.f)};
      X4[o0 + 1] = {fmaxf(v[4], 0.f), fmaxf(v[5], 0.f), fmaxf(v[6], 0.f), fmaxf(v[7], 0.f)};
    } else if (MODE == MODE_GD) {
      float4 x0 = X4[o0], x1 = X4[o0 + 1];
      X4[o0] = {x0.x + v[0], x0.y + v[1], x0.z + v[2], x0.w + v[3]};
      X4[o0 + 1] = {x1.x + v[4], x1.y + v[5], x1.z + v[6], x1.w + v[7]};
    } else {  // MODE_G0
      X4[o0] = {fmaxf(v[0], 0.f), fmaxf(v[1], 0.f), fmaxf(v[2], 0.f), fmaxf(v[3], 0.f)};
      X4[o0 + 1] = {fmaxf(v[4], 0.f), fmaxf(v[5], 0.f), fmaxf(v[6], 0.f), fmaxf(v[7], 0.f)};
    }
  }
}

// GAT softmax aggregation, two nodes per wave, both passes pipelined.
__global__ __launch_bounds__(256) void k_gat_agg(
    const int* __restrict__ off, const int* __restrict__ idx,
    const u32* __restrict__ Hgb, const float* __restrict__ al,
    const float* __restrict__ bias, float* __restrict__ X,
    float* __restrict__ R, int n) {
  int lane = threadIdx.x & 63;
  int wid = threadIdx.x >> 6;
  int d0 = blockIdx.x * 8 + wid * 2;
  if (d0 >= n) return;
  int d1 = d0 + 1;
  bool has1 = d1 < n;
  int rg = lane >> 3, cg = lane & 7;
  const uint4* H4b = (const uint4*)Hgb;
  float ald0 = al[(size_t)d0 * 16 + 8 + cg];
  float es0 = lrelu(al[(size_t)d0 * 16 + cg] + ald0);
  float ald1 = has1 ? al[(size_t)d1 * 16 + 8 + cg] : 0.f;
  float es1 = has1 ? lrelu(al[(size_t)d1 * 16 + cg] + ald1) : 0.f;
  int beg0 = off[d0], end0 = off[d0 + 1];
  int beg1 = has1 ? off[d1] : 0, end1 = has1 ? off[d1 + 1] : 0;
  int cnt0 = end0 - beg0, cnt1 = end1 - beg1;
  int cmax = cnt0 > cnt1 ? cnt0 : cnt1;
  // pass 1: per-head max
  float m0 = es0, m1 = es1;
  for (int base = 0; base < cmax; base += 64) {
    int c0 = cnt0 - base; if (c0 > 64) c0 = 64;
    int c1 = cnt1 - base; if (c1 > 64) c1 = 64;
    int sidx0 = (lane < c0) ? idx[beg0 + base + lane] : -1;
    int sidx1 = (lane < c1) ? idx[beg1 + base + lane] : -1;
    int hi = c0 > c1 ? c0 : c1;
    int nI = (hi + 7) >> 3;
    int j = 0;
    for (; j + 2 <= nI; j += 2) {
      int s00 = __shfl(sidx0, j * 8 + rg, 64);
      int s01 = __shfl(sidx0, j * 8 + 8 + rg, 64);
      int s10 = __shfl(sidx1, j * 8 + rg, 64);
      int s11 = __shfl(sidx1, j * 8 + 8 + rg, 64);
      float a00 = al[(size_t)(s00 >= 0 ? s00 : 0) * 16 + cg];
      float a01 = al[(size_t)(s01 >= 0 ? s01 : 0) * 16 + cg];
      float a10 = al[(size_t)(s10 >= 0 ? s10 : 0) * 16 + cg];
      float a11 = al[(size_t)(s11 >= 0 ? s11 : 0) * 16 + cg];
      if (s00 >= 0) m0 = fmaxf(m0, lrelu(a00 + ald0));
      if (s01 >= 0) m0 = fmaxf(m0, lrelu(a01 + ald0));
      if (s10 >= 0) m1 = fmaxf(m1, lrelu(a10 + ald1));
      if (s11 >= 0) m1 = fmaxf(m1, lrelu(a11 + ald1));
    }
    if (j < nI) {
      int s00 = __shfl(sidx0, j * 8 + rg, 64);
      int s10 = __shfl(sidx1, j * 8 + rg, 64);
      float a00 = al[(size_t)(s00 >= 0 ? s00 : 0) * 16 + cg];
      float a10 = al[(size_t)(s10 >= 0 ? s10 : 0) * 16 + cg];
      if (s00 >= 0) m0 = fmaxf(m0, lrelu(a00 + ald0));
      if (s10 >= 0) m1 = fmaxf(m1, lrelu(a10 + ald1));
    }
  }
#pragma unroll
  for (int mm = 8; mm < 64; mm <<= 1) {
    m0 = fmaxf(m0, __shfl_xor(m0, mm, 64));
    m1 = fmaxf(m1, __shfl_xor(m1, mm, 64));
  }
  // pass 2: weighted sum
  float den0 = 0.f, den1 = 0.f;
  float acc0[8], acc1[8];
#pragma unroll
  for (int i = 0; i < 8; ++i) { acc0[i] = 0.f; acc1[i] = 0.f; }
  for (int base = 0; base < cmax; base += 64) {
    int c0 = cnt0 - base; if (c0 > 64) c0 = 64;
    int c1 = cnt1 - base; if (c1 > 64) c1 = 64;
    int sidx0 = (lane < c0) ? idx[beg0 + base + lane] : -1;
    int sidx1 = (lane < c1) ? idx[beg1 + base + lane] : -1;
    int hi = c0 > c1 ? c0 : c1;
    int nI = (hi + 7) >> 3;
    int j = 0;
    for (; j + 2 <= nI; j += 2) {
      int s00 = __shfl(sidx0, j * 8 + rg, 64);
      int s01 = __shfl(sidx0, j * 8 + 8 + rg, 64);
      int s10 = __shfl(sidx1, j * 8 + rg, 64);
      int s11 = __shfl(sidx1, j * 8 + 8 + rg, 64);
      size_t a00 = (size_t)(s00 >= 0 ? s00 : 0);
      size_t a01 = (size_t)(s01 >= 0 ? s01 : 0);
      size_t a10 = (size_t)(s10 >= 0 ? s10 : 0);
      size_t a11 = (size_t)(s11 >= 0 ? s11 : 0);
      float l00 = al[a00 * 16 + cg];
      float l01 = al[a01 * 16 + cg];
      float l10 = al[a10 * 16 + cg];
      float l11 = al[a11 * 16 + cg];
      uint4 q00 = H4b[a00 * 8 + cg];
      uint4 q01 = H4b[a01 * 8 + cg];
      uint4 q10 = H4b[a10 * 8 + cg];
      uint4 q11 = H4b[a11 * 8 + cg];
      float p00 = (s00 >= 0) ? __expf(lrelu(l00 + ald0) - m0) : 0.f;
      float p01 = (s01 >= 0) ? __expf(lrelu(l01 + ald0) - m0) : 0.f;
      float p10 = (s10 >= 0) ? __expf(lrelu(l10 + ald1) - m1) : 0.f;
      float p11 = (s11 >= 0) ? __expf(lrelu(l11 + ald1) - m1) : 0.f;
      den0 += p00; fma8(acc0, p00, q00);
      den0 += p01; fma8(acc0, p01, q01);
      den1 += p10; fma8(acc1, p10, q10);
      den1 += p11; fma8(acc1, p11, q11);
    }
    if (j < nI) {
      int s00 = __shfl(sidx0, j * 8 + rg, 64);
      int s10 = __shfl(sidx1, j * 8 + rg, 64);
      size_t a00 = (size_t)(s00 >= 0 ? s00 : 0);
      size_t a10 = (size_t)(s10 >= 0 ? s10 : 0);
      float l00 = al[a00 * 16 + cg];
      float l10 = al[a10 * 16 + cg];
      uint4 q00 = H4b[a00 * 8 + cg];
      uint4 q10 = H4b[a10 * 8 + cg];
      float p00 = (s00 >= 0) ? __expf(lrelu(l00 + ald0) - m0) : 0.f;
      float p10 = (s10 >= 0) ? __expf(lrelu(l10 + ald1) - m1) : 0.f;
      den0 += p00; fma8(acc0, p00, q00);
      den1 += p10; fma8(acc1, p10, q10);
    }
  }
#pragma unroll
  for (int mm = 8; mm < 64; mm <<= 1) {
#pragma unroll
    for (int i = 0; i < 8; ++i) {
      acc0[i] += __shfl_xor(acc0[i], mm, 64);
      acc1[i] += __shfl_xor(acc1[i], mm, 64);
    }
    den0 += __shfl_xor(den0, mm, 64);
    den1 += __shfl_xor(den1, mm, 64);
  }
  if (rg != 0) return;
#pragma unroll
  for (int nd = 0; nd < 2; ++nd) {
    if (nd == 1 && !has1) break;
    int d = nd == 0 ? d0 : d1;
    float* acc = nd == 0 ? acc0 : acc1;
    float es = nd == 0 ? es0 : es1;
    float m = nd == 0 ? m0 : m1;
    float den = nd == 0 ? den0 : den1;
    float pself = __expf(es - m);
    uint4 hw = H4b[(size_t)d * 8 + cg];
    float hs[8] = {bf_lo(hw.x), bf_hi(hw.x), bf_lo(hw.y), bf_hi(hw.y),
                   bf_lo(hw.z), bf_hi(hw.z), bf_lo(hw.w), bf_hi(hw.w)};
#pragma unroll
    for (int i = 0; i < 8; ++i) acc[i] = fmaf(pself, hs[i], acc[i]);
    den += pself;
    float inv = 1.f / den;
    float4 b0 = ((const float4*)bias)[cg * 2];
    float4 b1 = ((const float4*)bias)[cg * 2 + 1];
    float bv[8] = {b0.x, b0.y, b0.z, b0.w, b1.x, b1.y, b1.z, b1.w};
    float v[8];
#pragma unroll
    for (int i = 0; i < 8; ++i) v[i] = acc[i] * inv + bv[i];
    size_t o0 = (size_t)d * 16 + cg * 2;
    ((float4*)X)[o0] = {v[0], v[1], v[2], v[3]};
    ((float4*)X)[o0 + 1] = {v[4], v[5], v[6], v[7]};
    ((float4*)R)[o0] = {v[0], v[1], v[2], v[3]};
    ((float4*)R)[o0 + 1] = {v[4], v[5], v[6], v[7]};
  }
}

// ------------------------------- final linear ------------------------------

__global__ __launch_bounds__(256) void k_fc(
    const float* __restrict__ X, const float* __restrict__ W,
    const float* __restrict__ b, float* __restrict__ out, int n) {
  __shared__ float Wl[640];
  __shared__ float bl[10];
  for (int i = threadIdx.x; i < 640; i += 256) Wl[i] = W[i];
  if (threadIdx.x < 10) bl[threadIdx.x] = b[threadIdx.x];
  __syncthreads();
  int r = blockIdx.x * blockDim.x + threadIdx.x;
  if (r >= n) return;
  float acc[10];
#pragma unroll
  for (int c = 0; c < 10; ++c) acc[c] = bl[c];
#pragma unroll
  for (int k = 0; k < 64; ++k) {
    float xv = X[(size_t)r * 64 + k];
#pragma unroll
    for (int c = 0; c < 10; ++c) acc[c] = fmaf(xv, Wl[k * 10 + c], acc[c]);
  }
#pragma unroll
  for (int c = 0; c < 10; ++c) out[(size_t)r * 10 + c] = acc[c];
}

// --------------------------------- launch ----------------------------------

extern "C" void kernel_launch(void* const* d_in, const int* in_sizes, int n_in,
                              void* d_out, int out_size, void* d_ws, size_t ws_size,
                              hipStream_t stream) {
  const float* x_in  = (const float*)d_in[0];
  const int*   ei    = (const int*)d_in[1];
  const float* gatW  = (const float*)d_in[2];
  const float* gatAs = (const float*)d_in[3];
  const float* gatAd = (const float*)d_in[4];
  const float* gatB  = (const float*)d_in[5];
  const float* gcnW  = (const float*)d_in[6];
  const float* gcnB  = (const float*)d_in[7];
  const float* fcW   = (const float*)d_in[8];
  const float* fcB   = (const float*)d_in[9];
  float* out = (float*)d_out;

  const int N = in_sizes[0] / 64;
  const int E = in_sizes[1] / 2;
  const int NB = (N + RNGB - 1) >> BSH;
  const int chunk = (E + GEB - 1) / GEB;

  char* ws = (char*)d_ws;
  size_t o = 0;
  auto alloc = [&](size_t bytes) -> char* {
    char* p = ws + o;
    o = (o + bytes + 255) & ~(size_t)255;
    return p;
  };
  int* offA    = (int*)alloc((size_t)(N + 1) * 4);
  int* offB    = (int*)alloc((size_t)(N + 1) * 4);
  float* dis   = (float*)alloc((size_t)N * 4);
  int* idxA    = (int*)alloc((size_t)E * 4);
  int* idxB    = (int*)alloc((size_t)E * 4);
  int2* pairsA = (int2*)alloc((size_t)E * 8);
  int2* pairsB = (int2*)alloc((size_t)E * 8);
  int* gHistA  = (int*)alloc((size_t)GEB * NB * 4);
  int* gHistB  = (int*)alloc((size_t)GEB * NB * 4);
  int* totA    = (int*)alloc((size_t)NB * 4);
  int* totB    = (int*)alloc((size_t)NB * 4);
  int* baseA   = (int*)alloc((size_t)NB * 4);
  int* baseB   = (int*)alloc((size_t)NB * 4);
  float* al    = (float*)alloc((size_t)N * 16 * 4);
  u32* B0      = (u32*)alloc((size_t)N * 32 * 4);
  u32* B1      = (u32*)alloc((size_t)N * 32 * 4);
  float* X     = (float*)alloc((size_t)N * 64 * 4);
  float* R     = (float*)alloc((size_t)N * 64 * 4);

  int nbN = (N + 255) / 256;
  int nbAgg = (N + 7) / 8;
  int nbG = (N + 63) / 64;

  // ---- CSR build: bucketed counting sort ----
  k_hist<<<GEB, 256, 0, stream>>>(ei, E, NB, chunk, gHistA, gHistB);
  k_colscan<<<NB, GEB, 0, stream>>>(gHistA, totA, NB);
  k_colscan<<<NB, GEB, 0, stream>>>(gHistB, totB, NB);
  k_bscan<<<1, 1024, 0, stream>>>(totA, totB, baseA, baseB, offA, offB, NB, N, E);
  k_scatter<<<GEB, 256, 0, stream>>>(ei, E, NB, chunk, gHistA, gHistB,
                                     baseA, baseB, pairsA, pairsB);
  k_bucket<0><<<NB, 256, 0, stream>>>(pairsA, baseA, totA, offA, idxA, nullptr, N);
  k_bucket<1><<<NB, 256, 0, stream>>>(pairsB, baseB, totB, offB, idxB, dis, N);

  // ---- random walk: 5 steps (fp32 in -> bf16 ping-pong) ----
  k_agg<MODE_RW1><<<nbAgg, 256, 0, stream>>>(offA, idxA, x_in, nullptr, nullptr, nullptr, nullptr, nullptr, B0, N);
  k_agg<MODE_RW><<<nbAgg, 256, 0, stream>>>(offA, idxA, nullptr, B0, nullptr, nullptr, nullptr, nullptr, B1, N);
  k_agg<MODE_RW><<<nbAgg, 256, 0, stream>>>(offA, idxA, nullptr, B1, nullptr, nullptr, nullptr, nullptr, B0, N);
  k_agg<MODE_RW><<<nbAgg, 256, 0, stream>>>(offA, idxA, nullptr, B0, nullptr, nullptr, nullptr, nullptr, B1, N);
  k_agg<MODE_RW><<<nbAgg, 256, 0, stream>>>(offA, idxA, nullptr, B1, nullptr, nullptr, nullptr, nullptr, B0, N);

  // ---- GAT ----
  k_gat_gemm<<<nbG, 256, 0, stream>>>(B0, gatW, gatAs, gatAd, B1, al, N);
  k_gat_agg<<<nbAgg, 256, 0, stream>>>(offB, idxB, B1, al, gatB, X, R, N);

  // ---- residual GCN ----
  for (int i = 0; i < 12; ++i) {
    k_gemm64<<<nbG, 256, 0, stream>>>(X, gcnW + i * 4096, dis, B0, N);
    if (i == 0)
      k_agg<MODE_G0><<<nbAgg, 256, 0, stream>>>(offB, idxB, nullptr, B0, dis, gcnB + i * 64, nullptr, X, nullptr, N);
    else
      k_agg<MODE_GR><<<nbAgg, 256, 0, stream>>>(offB, idxB, nullptr, B0, dis, gcnB + i * 64, R, X, nullptr, N);
    if (i < 11) {
      int j = (i == 0) ? 11 : i - 1;
      k_gemm64<<<nbG, 256, 0, stream>>>(X, gcnW + j * 4096, dis, B0, N);
      k_agg<MODE_GD><<<nbAgg, 256, 0, stream>>>(offB, idxB, nullptr, B0, dis, gcnB + j * 64, nullptr, X, nullptr, N);
    }
  }

  // ---- final linear ----
  k_fc<<<nbN, 256, 0, stream>>>(X, fcW, fcB, out, N);
}